// Round 1
// baseline (2093.794 us; speedup 1.0000x reference)
//
#include <hip/hip_runtime.h>
#include <hip/hip_bf16.h>

#define NN 8192
#define NE 262144

typedef float v2 __attribute__((ext_vector_type(2)));
typedef float v4 __attribute__((ext_vector_type(4)));

__device__ __forceinline__ float sigm(float x) { return 1.0f / (1.0f + __expf(-x)); }
// robust tanh: no NaN at +/-inf of exp
__device__ __forceinline__ float tanh_(float x) { return 1.0f - 2.0f / (__expf(2.0f * x) + 1.0f); }

// ---------------- prep: transposed LSTM weights + summed biases ----------------
// WT0[144][512]: k<16 -> w_ih0[g][k], else w_hh0[g][k-16]
// WT1[256][512]: k<128 -> w_ih1[g][k], else w_hh1[g][k-128]
// bias[0:512] = b_ih0+b_hh0 ; bias[512:1024] = b_ih1+b_hh1
__global__ void k_prep(const float* __restrict__ wih0, const float* __restrict__ whh0,
                       const float* __restrict__ bih0, const float* __restrict__ bhh0,
                       const float* __restrict__ wih1, const float* __restrict__ whh1,
                       const float* __restrict__ bih1, const float* __restrict__ bhh1,
                       float* __restrict__ WT0, float* __restrict__ WT1, float* __restrict__ bias) {
    int i = blockIdx.x * 256 + threadIdx.x;
    if (i < 73728) {
        int k = i >> 9, g = i & 511;
        WT0[i] = (k < 16) ? wih0[g * 16 + k] : whh0[g * 128 + (k - 16)];
    } else if (i < 204800) {
        int j = i - 73728;
        int k = j >> 9, g = j & 511;
        WT1[j] = (k < 128) ? wih1[g * 128 + k] : whh1[g * 128 + (k - 128)];
    } else if (i < 205312) {
        int g = i - 204800;
        bias[g] = bih0[g] + bhh0[g];
    } else if (i < 205824) {
        int g = i - 205312;
        bias[512 + g] = bih1[g] + bhh1[g];
    }
}

// ---------------- GCN ----------------
__global__ void k_deg_init(float* __restrict__ dis) {
    int i = blockIdx.x * 256 + threadIdx.x;
    if (i < NN) dis[i] = 1.0f;  // self-loop
}
__global__ void k_deg_count(const int* __restrict__ dst, float* __restrict__ dis) {
    int i = blockIdx.x * 256 + threadIdx.x;
    if (i < NE) atomicAdd(&dis[dst[i]], 1.0f);
}
__global__ void k_dis(float* __restrict__ dis) {
    int i = blockIdx.x * 256 + threadIdx.x;
    if (i < NN) dis[i] = rsqrtf(dis[i]);
}
// hs[r][c] = (sum_k in[r][k]*w[k][c]) * dis[r]   (one wave per row, lane=col, C=64)
__global__ __launch_bounds__(256) void k_gcn_gemm(const float* __restrict__ in, const float* __restrict__ w,
                                                  const float* __restrict__ dis, float* __restrict__ hs, int K) {
    int wv = threadIdx.x >> 6, ln = threadIdx.x & 63;
    int row = blockIdx.x * 4 + wv;
    const float* xp = in + (size_t)row * K;
    float a = 0.f;
    for (int k = 0; k < K; ++k) a += xp[k] * w[k * 64 + ln];
    hs[(size_t)row * 64 + ln] = a * dis[row];
}
// acc[d] += hs[s] for each edge (one wave per edge, lane=feature)
__global__ __launch_bounds__(256) void k_scatter(const int* __restrict__ src, const int* __restrict__ dst,
                                                 const float* __restrict__ hs, float* __restrict__ acc) {
    int ln = threadIdx.x & 63;
    int wid = (blockIdx.x * blockDim.x + threadIdx.x) >> 6;
    int nw = (gridDim.x * blockDim.x) >> 6;
    for (int e = wid; e < NE; e += nw) {
        int s = src[e], d = dst[e];
        atomicAdd(&acc[(size_t)d * 64 + ln], hs[(size_t)s * 64 + ln]);
    }
}
// out = relu( ((acc + hs_self)*dis + gcn_b) * bn_g*rsqrt(1+eps) + bn_b )
__global__ void k_gcn_finish(const float* __restrict__ acc, const float* __restrict__ hs,
                             const float* __restrict__ dis, const float* __restrict__ gb,
                             const float* __restrict__ bng, const float* __restrict__ bnb,
                             float* __restrict__ out) {
    int i = blockIdx.x * 256 + threadIdx.x;  // < NN*64
    int d = i >> 6, c = i & 63;
    float rs = rsqrtf(1.0f + 1e-5f);
    float v = (acc[i] + hs[i]) * dis[d] + gb[c];
    v = v * (bng[c] * rs) + bnb[c];
    out[i] = fmaxf(v, 0.f);
}

// ---------------- fused 2-layer LSTM ----------------
// 256 blocks x 256 threads; block owns 32 rows; wave owns 8 rows.
// lane ln owns gate columns {q*128 + 2*ln + jj} for q=0..3, jj=0..1 -> i/f/g/o local.
__global__ __launch_bounds__(256) void k_lstm(const float* __restrict__ dyn, const float* __restrict__ WT0,
                                              const float* __restrict__ WT1, const float* __restrict__ bias,
                                              float* __restrict__ rnn) {
    __shared__ __align__(16) float x0[32][148];  // [row][k]: k<16 dyn_t, k>=16 h0
    __shared__ __align__(16) float x1[32][260];  // [row][k]: k<128 h0, k>=128 h1
    __shared__ __align__(16) float wt[8192];     // 16 x 512 weight tile

    const int tid = threadIdx.x;
    const int wv = tid >> 6;
    const int ln = tid & 63;
    const int wr = wv * 8;                // wave's first local row
    const int row0 = blockIdx.x * 32;     // global row base

    for (int i = tid; i < 32 * 148; i += 256) (&x0[0][0])[i] = 0.f;
    for (int i = tid; i < 32 * 260; i += 256) (&x1[0][0])[i] = 0.f;

    float bs0[8], bs1[8];
#pragma unroll
    for (int q = 0; q < 4; ++q) {
        bs0[q * 2 + 0] = bias[q * 128 + 2 * ln + 0];
        bs0[q * 2 + 1] = bias[q * 128 + 2 * ln + 1];
        bs1[q * 2 + 0] = bias[512 + q * 128 + 2 * ln + 0];
        bs1[q * 2 + 1] = bias[512 + q * 128 + 2 * ln + 1];
    }
    float c0[16], c1[16];
#pragma unroll
    for (int i = 0; i < 16; ++i) { c0[i] = 0.f; c1[i] = 0.f; }

    // prefetch weight tile 0 (WT0 tile 0) into registers
    int tile = 0;
    v4 vg[8];
#pragma unroll
    for (int r = 0; r < 8; ++r) vg[r] = *(const v4*)(WT0 + r * 1024 + tid * 4);

    __syncthreads();  // LDS zero-init visible to all

#pragma unroll 1
    for (int t = 0; t < 32; ++t) {
        // load dyn[:, t, :] for this wave's 8 rows (lane: row=ln>>3, d pair=(ln&7)*2)
        {
            int rr = ln >> 3, d0 = (ln & 7) * 2;
            const float* p = dyn + (size_t)(row0 + wr + rr) * 512 + t * 16 + d0;
            v2 dv = *(const v2*)p;
            *(v2*)&x0[wr + rr][d0] = dv;
        }
        float acc[64];
        // ================= layer 0 GEMM (K=144, 9 tiles) =================
#pragma unroll
        for (int r = 0; r < 8; ++r)
#pragma unroll
            for (int i = 0; i < 8; ++i) acc[r * 8 + i] = bs0[i];
#pragma unroll 1
        for (int kt = 0; kt < 9; ++kt) {
            int nxt = tile + 1; if (nxt == 25) nxt = 0;
            const float* np = (nxt < 9) ? (WT0 + nxt * 8192) : (WT1 + (nxt - 9) * 8192);
            v4 vg2[8];
#pragma unroll
            for (int r = 0; r < 8; ++r) vg2[r] = *(const v4*)(np + r * 1024 + tid * 4);
            __syncthreads();  // everyone done reading wt (previous tile)
#pragma unroll
            for (int r = 0; r < 8; ++r) *(v4*)(wt + r * 1024 + tid * 4) = vg[r];
            __syncthreads();  // wt ready
            const int kb = kt * 16;
#pragma unroll
            for (int k4 = 0; k4 < 4; ++k4) {
                v4 xv[8];
#pragma unroll
                for (int r = 0; r < 8; ++r) xv[r] = *(const v4*)&x0[wr + r][kb + k4 * 4];
#pragma unroll
                for (int kk = 0; kk < 4; ++kk) {
                    const float* wrow = wt + (k4 * 4 + kk) * 512 + 2 * ln;
                    v2 w0 = *(const v2*)(wrow);
                    v2 w1 = *(const v2*)(wrow + 128);
                    v2 w2 = *(const v2*)(wrow + 256);
                    v2 w3 = *(const v2*)(wrow + 384);
#pragma unroll
                    for (int r = 0; r < 8; ++r) {
                        float x = xv[r][kk];
                        acc[r * 8 + 0] += x * w0[0]; acc[r * 8 + 1] += x * w0[1];
                        acc[r * 8 + 2] += x * w1[0]; acc[r * 8 + 3] += x * w1[1];
                        acc[r * 8 + 4] += x * w2[0]; acc[r * 8 + 5] += x * w2[1];
                        acc[r * 8 + 6] += x * w3[0]; acc[r * 8 + 7] += x * w3[1];
                    }
                }
            }
#pragma unroll
            for (int r = 0; r < 8; ++r) vg[r] = vg2[r];
            tile = nxt;
        }
        // ================= layer 0 elementwise =================
#pragma unroll
        for (int r = 0; r < 8; ++r) {
            v2 hv;
#pragma unroll
            for (int jj = 0; jj < 2; ++jj) {
                float iv = acc[r * 8 + 0 + jj], fv = acc[r * 8 + 2 + jj];
                float gv = acc[r * 8 + 4 + jj], ov = acc[r * 8 + 6 + jj];
                float c = sigm(fv) * c0[r * 2 + jj] + sigm(iv) * tanh_(gv);
                c0[r * 2 + jj] = c;
                hv[jj] = sigm(ov) * tanh_(c);
            }
            *(v2*)&x0[wr + r][16 + 2 * ln] = hv;   // next step's layer-0 input
            *(v2*)&x1[wr + r][2 * ln] = hv;        // this step's layer-1 input
        }
        // ================= layer 1 GEMM (K=256, 16 tiles) =================
#pragma unroll
        for (int r = 0; r < 8; ++r)
#pragma unroll
            for (int i = 0; i < 8; ++i) acc[r * 8 + i] = bs1[i];
#pragma unroll 1
        for (int kt = 0; kt < 16; ++kt) {
            int nxt = tile + 1; if (nxt == 25) nxt = 0;
            const float* np = (nxt < 9) ? (WT0 + nxt * 8192) : (WT1 + (nxt - 9) * 8192);
            v4 vg2[8];
#pragma unroll
            for (int r = 0; r < 8; ++r) vg2[r] = *(const v4*)(np + r * 1024 + tid * 4);
            __syncthreads();
#pragma unroll
            for (int r = 0; r < 8; ++r) *(v4*)(wt + r * 1024 + tid * 4) = vg[r];
            __syncthreads();
            const int kb = kt * 16;
#pragma unroll
            for (int k4 = 0; k4 < 4; ++k4) {
                v4 xv[8];
#pragma unroll
                for (int r = 0; r < 8; ++r) xv[r] = *(const v4*)&x1[wr + r][kb + k4 * 4];
#pragma unroll
                for (int kk = 0; kk < 4; ++kk) {
                    const float* wrow = wt + (k4 * 4 + kk) * 512 + 2 * ln;
                    v2 w0 = *(const v2*)(wrow);
                    v2 w1 = *(const v2*)(wrow + 128);
                    v2 w2 = *(const v2*)(wrow + 256);
                    v2 w3 = *(const v2*)(wrow + 384);
#pragma unroll
                    for (int r = 0; r < 8; ++r) {
                        float x = xv[r][kk];
                        acc[r * 8 + 0] += x * w0[0]; acc[r * 8 + 1] += x * w0[1];
                        acc[r * 8 + 2] += x * w1[0]; acc[r * 8 + 3] += x * w1[1];
                        acc[r * 8 + 4] += x * w2[0]; acc[r * 8 + 5] += x * w2[1];
                        acc[r * 8 + 6] += x * w3[0]; acc[r * 8 + 7] += x * w3[1];
                    }
                }
            }
#pragma unroll
            for (int r = 0; r < 8; ++r) vg[r] = vg2[r];
            tile = nxt;
        }
        // ================= layer 1 elementwise =================
#pragma unroll
        for (int r = 0; r < 8; ++r) {
            v2 hv;
#pragma unroll
            for (int jj = 0; jj < 2; ++jj) {
                float iv = acc[r * 8 + 0 + jj], fv = acc[r * 8 + 2 + jj];
                float gv = acc[r * 8 + 4 + jj], ov = acc[r * 8 + 6 + jj];
                float c = sigm(fv) * c1[r * 2 + jj] + sigm(iv) * tanh_(gv);
                c1[r * 2 + jj] = c;
                hv[jj] = sigm(ov) * tanh_(c);
            }
            *(v2*)&x1[wr + r][128 + 2 * ln] = hv;  // next step's layer-1 recurrent input
            if (t == 31) *(v2*)&rnn[(size_t)(row0 + wr + r) * 128 + 2 * ln] = hv;
        }
    }
}

// ---------------- head: fc1 + bn + relu, fc2 + relu, out ----------------
__global__ __launch_bounds__(256) void k_head(const float* __restrict__ gnn, const float* __restrict__ rnn,
                                              const float* __restrict__ fc1w, const float* __restrict__ fc1b,
                                              const float* __restrict__ fbng, const float* __restrict__ fbnb,
                                              const float* __restrict__ fc2w, const float* __restrict__ fc2b,
                                              const float* __restrict__ outw, const float* __restrict__ outb,
                                              float* __restrict__ out) {
    __shared__ __align__(16) float xin[32][196];
    __shared__ __align__(16) float xh2[32][132];
    __shared__ __align__(16) float xh3[32][68];
    const int tid = threadIdx.x;
    const int r0 = blockIdx.x * 32;
    for (int i = tid; i < 32 * 64; i += 256) { int r = i >> 6, c = i & 63; xin[r][c] = gnn[(size_t)(r0 + r) * 64 + c]; }
    for (int i = tid; i < 32 * 128; i += 256) { int r = i >> 7, c = i & 127; xin[r][64 + c] = rnn[(size_t)(r0 + r) * 128 + c]; }
    __syncthreads();
    const int wv = tid >> 6, ln = tid & 63, wr = wv * 8;
    const float rs = rsqrtf(1.0f + 1e-5f);
    float a[8][2];
    float b0 = fc1b[2 * ln], b1 = fc1b[2 * ln + 1];
#pragma unroll
    for (int r = 0; r < 8; ++r) { a[r][0] = b0; a[r][1] = b1; }
    for (int k = 0; k < 192; ++k) {
        v2 w = *(const v2*)&fc1w[k * 128 + 2 * ln];
#pragma unroll
        for (int r = 0; r < 8; ++r) { float x = xin[wr + r][k]; a[r][0] += x * w[0]; a[r][1] += x * w[1]; }
    }
    float s0 = fbng[2 * ln] * rs, s1 = fbng[2 * ln + 1] * rs;
    float bb0 = fbnb[2 * ln], bb1 = fbnb[2 * ln + 1];
#pragma unroll
    for (int r = 0; r < 8; ++r) {
        v2 h;
        h[0] = fmaxf(a[r][0] * s0 + bb0, 0.f);
        h[1] = fmaxf(a[r][1] * s1 + bb1, 0.f);
        *(v2*)&xh2[wr + r][2 * ln] = h;
    }
    __syncthreads();
    float a2[8];
    float b2 = fc2b[ln];
#pragma unroll
    for (int r = 0; r < 8; ++r) a2[r] = b2;
    for (int k = 0; k < 128; ++k) {
        float w = fc2w[k * 64 + ln];
#pragma unroll
        for (int r = 0; r < 8; ++r) a2[r] += xh2[wr + r][k] * w;
    }
#pragma unroll
    for (int r = 0; r < 8; ++r) xh3[wr + r][ln] = fmaxf(a2[r], 0.f);
    __syncthreads();
    if (ln < 10) {
#pragma unroll
        for (int r = 0; r < 8; ++r) {
            float a3 = outb[ln];
            for (int k = 0; k < 64; ++k) a3 += xh3[wr + r][k] * outw[k * 10 + ln];
            out[(size_t)(r0 + wr + r) * 10 + ln] = a3;
        }
    }
}

extern "C" void kernel_launch(void* const* d_in, const int* in_sizes, int n_in,
                              void* d_out, int out_size, void* d_ws, size_t ws_size,
                              hipStream_t stream) {
    const float* dyn  = (const float*)d_in[0];
    const float* xs   = (const float*)d_in[1];
    const int*   ei   = (const int*)d_in[2];
    const float* g1w  = (const float*)d_in[3];
    const float* g1b  = (const float*)d_in[4];
    const float* g2w  = (const float*)d_in[5];
    const float* g2b  = (const float*)d_in[6];
    const float* bn1g = (const float*)d_in[7];
    const float* bn1b = (const float*)d_in[8];
    const float* bn2g = (const float*)d_in[9];
    const float* bn2b = (const float*)d_in[10];
    const float* wih0 = (const float*)d_in[11];
    const float* whh0 = (const float*)d_in[12];
    const float* bih0 = (const float*)d_in[13];
    const float* bhh0 = (const float*)d_in[14];
    const float* wih1 = (const float*)d_in[15];
    const float* whh1 = (const float*)d_in[16];
    const float* bih1 = (const float*)d_in[17];
    const float* bhh1 = (const float*)d_in[18];
    const float* fc1w = (const float*)d_in[19];
    const float* fc1b = (const float*)d_in[20];
    const float* fbng = (const float*)d_in[21];
    const float* fbnb = (const float*)d_in[22];
    const float* fc2w = (const float*)d_in[23];
    const float* fc2b = (const float*)d_in[24];
    const float* outw = (const float*)d_in[25];
    const float* outb = (const float*)d_in[26];
    float* out = (float*)d_out;

    float* w = (float*)d_ws;
    float* WT0  = w + 0;        // 73728
    float* WT1  = w + 73728;    // 131072
    float* bias = w + 204800;   // 1024
    float* dis  = w + 205824;   // 8192
    float* hs   = w + 214016;   // 524288
    float* agg  = w + 738304;   // 524288
    float* y1   = w + 1262592;  // 524288
    float* gnn  = w + 1786880;  // 524288
    float* rnn  = w + 2311168;  // 1048576  (ends at 3359744 floats = ~12.8 MB)

    const int* srcp = ei;       // edge_index[0]
    const int* dstp = ei + NE;  // edge_index[1]

    // LSTM weight prep + GCN degree
    k_prep<<<805, 256, 0, stream>>>(wih0, whh0, bih0, bhh0, wih1, whh1, bih1, bhh1, WT0, WT1, bias);
    k_deg_init<<<32, 256, 0, stream>>>(dis);
    k_deg_count<<<1024, 256, 0, stream>>>(dstp, dis);
    k_dis<<<32, 256, 0, stream>>>(dis);
    // GCN layer 1
    k_gcn_gemm<<<2048, 256, 0, stream>>>(xs, g1w, dis, hs, 128);
    hipMemsetAsync(agg, 0, (size_t)524288 * sizeof(float), stream);
    k_scatter<<<512, 256, 0, stream>>>(srcp, dstp, hs, agg);
    k_gcn_finish<<<2048, 256, 0, stream>>>(agg, hs, dis, g1b, bn1g, bn1b, y1);
    // GCN layer 2
    k_gcn_gemm<<<2048, 256, 0, stream>>>(y1, g2w, dis, hs, 64);
    hipMemsetAsync(agg, 0, (size_t)524288 * sizeof(float), stream);
    k_scatter<<<512, 256, 0, stream>>>(srcp, dstp, hs, agg);
    k_gcn_finish<<<2048, 256, 0, stream>>>(agg, hs, dis, g2b, bn2g, bn2b, gnn);
    // fused 2-layer LSTM
    k_lstm<<<256, 256, 0, stream>>>(dyn, WT0, WT1, bias, rnn);
    // head
    k_head<<<256, 256, 0, stream>>>(gnn, rnn, fc1w, fc1b, fbng, fbnb, fc2w, fc2b, outw, outb, out);
}

// Round 2
// 908.499 us; speedup vs baseline: 2.3047x; 2.3047x over previous
//
#include <hip/hip_runtime.h>
#include <hip/hip_bf16.h>

#define NN 8192
#define NE 262144

typedef float v2 __attribute__((ext_vector_type(2)));
typedef float v4 __attribute__((ext_vector_type(4)));
typedef float f4 __attribute__((ext_vector_type(4)));
typedef _Float16 h8 __attribute__((ext_vector_type(8)));

__device__ __forceinline__ float sigm(float x) { return 1.0f / (1.0f + __expf(-x)); }
__device__ __forceinline__ float tanh_(float x) { return 1.0f - 2.0f / (__expf(2.0f * x) + 1.0f); }

// ---------------- prep: f16 col-major-per-ktile LSTM weights + summed biases ----------------
// WB0[5][512][32]  f16 : layer0, K=160 (k<16: w_ih0[g][k]; 16<=k<144: w_hh0[g][k-16]; else 0)
// WB1[8][512][32]  f16 : layer1, K=256 (k<128: w_ih1[g][k]; else w_hh1[g][k-128])
// bias[0:512]=b_ih0+b_hh0 ; bias[512:1024]=b_ih1+b_hh1  (fp32)
__global__ void k_prep(const float* __restrict__ wih0, const float* __restrict__ whh0,
                       const float* __restrict__ bih0, const float* __restrict__ bhh0,
                       const float* __restrict__ wih1, const float* __restrict__ whh1,
                       const float* __restrict__ bih1, const float* __restrict__ bhh1,
                       _Float16* __restrict__ WB0, _Float16* __restrict__ WB1,
                       float* __restrict__ bias) {
    int i = blockIdx.x * 256 + threadIdx.x;
    if (i < 81920) {
        int kt = i >> 14, rem = i & 16383, g = rem >> 5, kk = rem & 31, k = kt * 32 + kk;
        float v = 0.f;
        if (k < 16) v = wih0[g * 16 + k];
        else if (k < 144) v = whh0[g * 128 + (k - 16)];
        WB0[i] = (_Float16)v;
    } else if (i < 212992) {
        int m = i - 81920;
        int kt = m >> 14, rem = m & 16383, g = rem >> 5, kk = rem & 31, k = kt * 32 + kk;
        float v = (k < 128) ? wih1[g * 128 + k] : whh1[g * 128 + (k - 128)];
        WB1[m] = (_Float16)v;
    } else if (i < 214016) {
        int g = i - 212992;
        bias[g] = (g < 512) ? (bih0[g] + bhh0[g]) : (bih1[g - 512] + bhh1[g - 512]);
    }
}

// ---------------- GCN (unchanged; ~4 us total) ----------------
__global__ void k_deg_init(float* __restrict__ dis) {
    int i = blockIdx.x * 256 + threadIdx.x;
    if (i < NN) dis[i] = 1.0f;
}
__global__ void k_deg_count(const int* __restrict__ dst, float* __restrict__ dis) {
    int i = blockIdx.x * 256 + threadIdx.x;
    if (i < NE) atomicAdd(&dis[dst[i]], 1.0f);
}
__global__ void k_dis(float* __restrict__ dis) {
    int i = blockIdx.x * 256 + threadIdx.x;
    if (i < NN) dis[i] = rsqrtf(dis[i]);
}
__global__ __launch_bounds__(256) void k_gcn_gemm(const float* __restrict__ in, const float* __restrict__ w,
                                                  const float* __restrict__ dis, float* __restrict__ hs, int K) {
    int wv = threadIdx.x >> 6, ln = threadIdx.x & 63;
    int row = blockIdx.x * 4 + wv;
    const float* xp = in + (size_t)row * K;
    float a = 0.f;
    for (int k = 0; k < K; ++k) a += xp[k] * w[k * 64 + ln];
    hs[(size_t)row * 64 + ln] = a * dis[row];
}
__global__ __launch_bounds__(256) void k_scatter(const int* __restrict__ src, const int* __restrict__ dst,
                                                 const float* __restrict__ hs, float* __restrict__ acc) {
    int ln = threadIdx.x & 63;
    int wid = (blockIdx.x * blockDim.x + threadIdx.x) >> 6;
    int nw = (gridDim.x * blockDim.x) >> 6;
    for (int e = wid; e < NE; e += nw) {
        int s = src[e], d = dst[e];
        atomicAdd(&acc[(size_t)d * 64 + ln], hs[(size_t)s * 64 + ln]);
    }
}
__global__ void k_gcn_finish(const float* __restrict__ acc, const float* __restrict__ hs,
                             const float* __restrict__ dis, const float* __restrict__ gb,
                             const float* __restrict__ bng, const float* __restrict__ bnb,
                             float* __restrict__ out) {
    int i = blockIdx.x * 256 + threadIdx.x;
    int d = i >> 6, c = i & 63;
    float rs = rsqrtf(1.0f + 1e-5f);
    float v = (acc[i] + hs[i]) * dis[d] + gb[c];
    v = v * (bng[c] * rs) + bnb[c];
    out[i] = fmaxf(v, 0.f);
}

// ---------------- fused 2-layer LSTM, f16 MFMA ----------------
// 256 blocks x 512 threads (8 waves). Block owns 32 rows (M=32 -> 2 m-tiles).
// Wave w owns hidden cols j in [16w,16w+16) across all 4 gate groups (n = q*128+16w).
// B-fragments loaded straight from global (L2-resident, col-major per ktile).
// A-fragments from swizzled LDS x0/x1. C/D: col=lane&15, row=(lane>>4)*4+reg.
__device__ __forceinline__ const h8* ards(const _Float16* base, int row, int k, int rsb) {
    int b = (row * rsb + k * 2) ^ ((row & 7) << 4);
    return (const h8*)((const char*)base + b);
}
__device__ __forceinline__ void hwr(_Float16* base, int row, int k, int rsb, _Float16 v) {
    int b = (row * rsb + k * 2) ^ ((row & 7) << 4);
    *(_Float16*)((char*)base + b) = v;
}

__global__ __launch_bounds__(512) void k_lstm(const float* __restrict__ dyn,
                                              const _Float16* __restrict__ WB0,
                                              const _Float16* __restrict__ WB1,
                                              const float* __restrict__ bias,
                                              float* __restrict__ rnn) {
    __shared__ __align__(16) _Float16 x0[32 * 192];  // row stride 384 B, swizzled. k<16 dyn, 16+j h0
    __shared__ __align__(16) _Float16 x1[32 * 256];  // row stride 512 B, swizzled. j: h0, 128+j: h1

    const int tid = threadIdx.x;
    const int wv = tid >> 6, ln = tid & 63;
    const int lr = ln & 15, kg = ln >> 4;
    const int j = wv * 16 + lr;           // hidden col 0..127 owned by this lane
    const int row0 = blockIdx.x * 32;

    for (int i = tid; i < 32 * 192; i += 512) x0[i] = (_Float16)0.f;
    for (int i = tid; i < 32 * 256; i += 512) x1[i] = (_Float16)0.f;

    float b0q[4], b1q[4];
#pragma unroll
    for (int q = 0; q < 4; ++q) { b0q[q] = bias[q * 128 + j]; b1q[q] = bias[512 + q * 128 + j]; }
    float c0[2][4], c1[2][4];
#pragma unroll
    for (int mt = 0; mt < 2; ++mt)
#pragma unroll
        for (int r = 0; r < 4; ++r) { c0[mt][r] = 0.f; c1[mt][r] = 0.f; }

    {   // dyn_0 -> x0
        int rr = tid >> 4, d = tid & 15;
        hwr(x0, rr, d, 384, (_Float16)dyn[(size_t)(row0 + rr) * 512 + d]);
    }
    __syncthreads();

#pragma unroll 1
    for (int t = 0; t < 32; ++t) {
        f4 acc[2][4];
        // ---- layer 0 GEMM: K=160 (5 ktiles) on x0 ----
#pragma unroll
        for (int q = 0; q < 4; ++q) { f4 z = {b0q[q], b0q[q], b0q[q], b0q[q]}; acc[0][q] = z; acc[1][q] = z; }
#pragma unroll
        for (int kt = 0; kt < 5; ++kt) {
            const int kb = kt * 32 + kg * 8;
            h8 a0 = *ards(x0, lr, kb, 384);
            h8 a1 = *ards(x0, 16 + lr, kb, 384);
            h8 bq[4];
#pragma unroll
            for (int q = 0; q < 4; ++q)
                bq[q] = *(const h8*)(WB0 + ((size_t)kt * 16384 + (q * 128 + j) * 32 + kg * 8));
#pragma unroll
            for (int q = 0; q < 4; ++q) {
                acc[0][q] = __builtin_amdgcn_mfma_f32_16x16x32_f16(a0, bq[q], acc[0][q], 0, 0, 0);
                acc[1][q] = __builtin_amdgcn_mfma_f32_16x16x32_f16(a1, bq[q], acc[1][q], 0, 0, 0);
            }
        }
        __syncthreads();  // (a) all x0 reads done
        // ---- layer 0 elementwise (lane-local i,f,g,o) ----
        float h0f[2][4];
#pragma unroll
        for (int mt = 0; mt < 2; ++mt)
#pragma unroll
            for (int r = 0; r < 4; ++r) {
                float iv = acc[mt][0][r], fv = acc[mt][1][r], gv = acc[mt][2][r], ov = acc[mt][3][r];
                float c = sigm(fv) * c0[mt][r] + sigm(iv) * tanh_(gv);
                c0[mt][r] = c;
                h0f[mt][r] = sigm(ov) * tanh_(c);
            }
#pragma unroll
        for (int mt = 0; mt < 2; ++mt)
#pragma unroll
            for (int r = 0; r < 4; ++r) {
                int rr = mt * 16 + kg * 4 + r;
                _Float16 hv = (_Float16)h0f[mt][r];
                hwr(x0, rr, 16 + j, 384, hv);  // next step's layer-0 input
                hwr(x1, rr, j, 512, hv);       // this step's layer-1 input
            }
        if (t < 31) {  // prefetch dyn_{t+1} (x0 dyn-slot reads done at (a))
            int rr = tid >> 4, d = tid & 15;
            hwr(x0, rr, d, 384, (_Float16)dyn[(size_t)(row0 + rr) * 512 + (t + 1) * 16 + d]);
        }
        __syncthreads();  // (b) h0 visible
        // ---- layer 1 GEMM: K=256 (8 ktiles) on x1 ----
#pragma unroll
        for (int q = 0; q < 4; ++q) { f4 z = {b1q[q], b1q[q], b1q[q], b1q[q]}; acc[0][q] = z; acc[1][q] = z; }
#pragma unroll
        for (int kt = 0; kt < 8; ++kt) {
            const int kb = kt * 32 + kg * 8;
            h8 a0 = *ards(x1, lr, kb, 512);
            h8 a1 = *ards(x1, 16 + lr, kb, 512);
            h8 bq[4];
#pragma unroll
            for (int q = 0; q < 4; ++q)
                bq[q] = *(const h8*)(WB1 + ((size_t)kt * 16384 + (q * 128 + j) * 32 + kg * 8));
#pragma unroll
            for (int q = 0; q < 4; ++q) {
                acc[0][q] = __builtin_amdgcn_mfma_f32_16x16x32_f16(a0, bq[q], acc[0][q], 0, 0, 0);
                acc[1][q] = __builtin_amdgcn_mfma_f32_16x16x32_f16(a1, bq[q], acc[1][q], 0, 0, 0);
            }
        }
        __syncthreads();  // (c) all x1 reads done
        // ---- layer 1 elementwise ----
#pragma unroll
        for (int mt = 0; mt < 2; ++mt)
#pragma unroll
            for (int r = 0; r < 4; ++r) {
                float iv = acc[mt][0][r], fv = acc[mt][1][r], gv = acc[mt][2][r], ov = acc[mt][3][r];
                float c = sigm(fv) * c1[mt][r] + sigm(iv) * tanh_(gv);
                c1[mt][r] = c;
                float h = sigm(ov) * tanh_(c);
                int rr = mt * 16 + kg * 4 + r;
                if (t < 31) hwr(x1, rr, 128 + j, 512, (_Float16)h);
                else rnn[(size_t)(row0 + rr) * 128 + j] = h;
            }
        // no barrier needed: next iter's layer-0 touches only x0; x1 WAR separated by next (b)
    }
}

// ---------------- head (unchanged) ----------------
__global__ __launch_bounds__(256) void k_head(const float* __restrict__ gnn, const float* __restrict__ rnn,
                                              const float* __restrict__ fc1w, const float* __restrict__ fc1b,
                                              const float* __restrict__ fbng, const float* __restrict__ fbnb,
                                              const float* __restrict__ fc2w, const float* __restrict__ fc2b,
                                              const float* __restrict__ outw, const float* __restrict__ outb,
                                              float* __restrict__ out) {
    __shared__ __align__(16) float xin[32][196];
    __shared__ __align__(16) float xh2[32][132];
    __shared__ __align__(16) float xh3[32][68];
    const int tid = threadIdx.x;
    const int r0 = blockIdx.x * 32;
    for (int i = tid; i < 32 * 64; i += 256) { int r = i >> 6, c = i & 63; xin[r][c] = gnn[(size_t)(r0 + r) * 64 + c]; }
    for (int i = tid; i < 32 * 128; i += 256) { int r = i >> 7, c = i & 127; xin[r][64 + c] = rnn[(size_t)(r0 + r) * 128 + c]; }
    __syncthreads();
    const int wv = tid >> 6, ln = tid & 63, wr = wv * 8;
    const float rs = rsqrtf(1.0f + 1e-5f);
    float a[8][2];
    float b0 = fc1b[2 * ln], b1 = fc1b[2 * ln + 1];
#pragma unroll
    for (int r = 0; r < 8; ++r) { a[r][0] = b0; a[r][1] = b1; }
    for (int k = 0; k < 192; ++k) {
        v2 w = *(const v2*)&fc1w[k * 128 + 2 * ln];
#pragma unroll
        for (int r = 0; r < 8; ++r) { float x = xin[wr + r][k]; a[r][0] += x * w[0]; a[r][1] += x * w[1]; }
    }
    float s0 = fbng[2 * ln] * rs, s1 = fbng[2 * ln + 1] * rs;
    float bb0 = fbnb[2 * ln], bb1 = fbnb[2 * ln + 1];
#pragma unroll
    for (int r = 0; r < 8; ++r) {
        v2 h;
        h[0] = fmaxf(a[r][0] * s0 + bb0, 0.f);
        h[1] = fmaxf(a[r][1] * s1 + bb1, 0.f);
        *(v2*)&xh2[wr + r][2 * ln] = h;
    }
    __syncthreads();
    float a2[8];
    float b2 = fc2b[ln];
#pragma unroll
    for (int r = 0; r < 8; ++r) a2[r] = b2;
    for (int k = 0; k < 128; ++k) {
        float w = fc2w[k * 64 + ln];
#pragma unroll
        for (int r = 0; r < 8; ++r) a2[r] += xh2[wr + r][k] * w;
    }
#pragma unroll
    for (int r = 0; r < 8; ++r) xh3[wr + r][ln] = fmaxf(a2[r], 0.f);
    __syncthreads();
    if (ln < 10) {
#pragma unroll
        for (int r = 0; r < 8; ++r) {
            float a3 = outb[ln];
            for (int k = 0; k < 64; ++k) a3 += xh3[wr + r][k] * outw[k * 10 + ln];
            out[(size_t)(r0 + wr + r) * 10 + ln] = a3;
        }
    }
}

extern "C" void kernel_launch(void* const* d_in, const int* in_sizes, int n_in,
                              void* d_out, int out_size, void* d_ws, size_t ws_size,
                              hipStream_t stream) {
    const float* dyn  = (const float*)d_in[0];
    const float* xs   = (const float*)d_in[1];
    const int*   ei   = (const int*)d_in[2];
    const float* g1w  = (const float*)d_in[3];
    const float* g1b  = (const float*)d_in[4];
    const float* g2w  = (const float*)d_in[5];
    const float* g2b  = (const float*)d_in[6];
    const float* bn1g = (const float*)d_in[7];
    const float* bn1b = (const float*)d_in[8];
    const float* bn2g = (const float*)d_in[9];
    const float* bn2b = (const float*)d_in[10];
    const float* wih0 = (const float*)d_in[11];
    const float* whh0 = (const float*)d_in[12];
    const float* bih0 = (const float*)d_in[13];
    const float* bhh0 = (const float*)d_in[14];
    const float* wih1 = (const float*)d_in[15];
    const float* whh1 = (const float*)d_in[16];
    const float* bih1 = (const float*)d_in[17];
    const float* bhh1 = (const float*)d_in[18];
    const float* fc1w = (const float*)d_in[19];
    const float* fc1b = (const float*)d_in[20];
    const float* fbng = (const float*)d_in[21];
    const float* fbnb = (const float*)d_in[22];
    const float* fc2w = (const float*)d_in[23];
    const float* fc2b = (const float*)d_in[24];
    const float* outw = (const float*)d_in[25];
    const float* outb = (const float*)d_in[26];
    float* out = (float*)d_out;

    _Float16* WB0 = (_Float16*)d_ws;          // 81920 f16
    _Float16* WB1 = WB0 + 81920;              // 131072 f16 (f16 region = 425984 B)
    float* fbase = (float*)((char*)d_ws + 425984);
    float* bias = fbase;                      // 1024
    float* dis  = fbase + 1024;               // 8192
    float* hs   = fbase + 9216;               // 524288
    float* agg  = fbase + 533504;             // 524288
    float* y1   = fbase + 1057792;            // 524288
    float* gnn  = fbase + 1582080;            // 524288
    float* rnn  = fbase + 2106368;            // 1048576

    const int* srcp = ei;
    const int* dstp = ei + NE;

    k_prep<<<836, 256, 0, stream>>>(wih0, whh0, bih0, bhh0, wih1, whh1, bih1, bhh1, WB0, WB1, bias);
    k_deg_init<<<32, 256, 0, stream>>>(dis);
    k_deg_count<<<1024, 256, 0, stream>>>(dstp, dis);
    k_dis<<<32, 256, 0, stream>>>(dis);
    k_gcn_gemm<<<2048, 256, 0, stream>>>(xs, g1w, dis, hs, 128);
    hipMemsetAsync(agg, 0, (size_t)524288 * sizeof(float), stream);
    k_scatter<<<512, 256, 0, stream>>>(srcp, dstp, hs, agg);
    k_gcn_finish<<<2048, 256, 0, stream>>>(agg, hs, dis, g1b, bn1g, bn1b, y1);
    k_gcn_gemm<<<2048, 256, 0, stream>>>(y1, g2w, dis, hs, 64);
    hipMemsetAsync(agg, 0, (size_t)524288 * sizeof(float), stream);
    k_scatter<<<512, 256, 0, stream>>>(srcp, dstp, hs, agg);
    k_gcn_finish<<<2048, 256, 0, stream>>>(agg, hs, dis, g2b, bn2g, bn2b, gnn);
    k_lstm<<<256, 512, 0, stream>>>(dyn, WB0, WB1, bias, rnn);
    k_head<<<256, 256, 0, stream>>>(gnn, rnn, fc1w, fc1b, fbng, fbnb, fc2w, fc2b, outw, outb, out);
}

// Round 3
// 555.720 us; speedup vs baseline: 3.7677x; 1.6348x over previous
//
#include <hip/hip_runtime.h>
#include <hip/hip_bf16.h>

#define NN 8192
#define NE 262144

typedef float v2 __attribute__((ext_vector_type(2)));
typedef float v4 __attribute__((ext_vector_type(4)));
typedef float f4 __attribute__((ext_vector_type(4)));
typedef _Float16 h8 __attribute__((ext_vector_type(8)));

__device__ __forceinline__ float sigm(float x) { return 1.0f / (1.0f + __expf(-x)); }
__device__ __forceinline__ float tanh_(float x) { return 1.0f - 2.0f / (__expf(2.0f * x) + 1.0f); }

// ---------------- prep ----------------
// WB0h[4][4][512][8] f16 : layer0 W_hh0, element ((kt*4+kg)*512+col)*8+idx = whh0[col][kt*32+kg*8+idx]
// TL[512][16]        f16 : layer0 W_ih0 transposed: TL[g][kd] = wih0[g][kd]
// WB1[8][512][32]    f16 : layer1, K=256 (k<128: w_ih1; else w_hh1), col-major per ktile
// bias[0:512]=b_ih0+b_hh0 ; bias[512:1024]=b_ih1+b_hh1 (fp32)
__global__ void k_prep(const float* __restrict__ wih0, const float* __restrict__ whh0,
                       const float* __restrict__ bih0, const float* __restrict__ bhh0,
                       const float* __restrict__ wih1, const float* __restrict__ whh1,
                       const float* __restrict__ bih1, const float* __restrict__ bhh1,
                       _Float16* __restrict__ WB0h, _Float16* __restrict__ TLg,
                       _Float16* __restrict__ WB1, float* __restrict__ bias) {
    int i = blockIdx.x * 256 + threadIdx.x;
    if (i < 65536) {
        int idx = i & 7, col = (i >> 3) & 511, kgq = (i >> 12) & 3, kt = i >> 14;
        int kh = kt * 32 + kgq * 8 + idx;  // 0..127
        WB0h[i] = (_Float16)whh0[col * 128 + kh];
    } else if (i < 73728) {
        int m = i - 65536;
        int kd = m & 15, g = m >> 4;
        TLg[m] = (_Float16)wih0[g * 16 + kd];
    } else if (i < 204800) {
        int m = i - 73728;
        int kt = m >> 14, rem = m & 16383, g = rem >> 5, kk = rem & 31, k = kt * 32 + kk;
        WB1[m] = (_Float16)((k < 128) ? wih1[g * 128 + k] : whh1[g * 128 + (k - 128)]);
    } else if (i < 205824) {
        int g = i - 204800;
        bias[g] = (g < 512) ? (bih0[g] + bhh0[g]) : (bih1[g - 512] + bhh1[g - 512]);
    }
}

// ---------------- GCN ----------------
__global__ void k_deg_init(float* __restrict__ dis) {
    int i = blockIdx.x * 256 + threadIdx.x;
    if (i < NN) dis[i] = 1.0f;
}
__global__ void k_deg_count(const int* __restrict__ dst, float* __restrict__ dis) {
    int i = blockIdx.x * 256 + threadIdx.x;
    if (i < NE) atomicAdd(&dis[dst[i]], 1.0f);
}
__global__ void k_dis(float* __restrict__ dis) {
    int i = blockIdx.x * 256 + threadIdx.x;
    if (i < NN) dis[i] = rsqrtf(dis[i]);
}
__global__ __launch_bounds__(256) void k_gcn_gemm(const float* __restrict__ in, const float* __restrict__ w,
                                                  const float* __restrict__ dis, float* __restrict__ hs, int K) {
    int wv = threadIdx.x >> 6, ln = threadIdx.x & 63;
    int row = blockIdx.x * 4 + wv;
    const float* xp = in + (size_t)row * K;
    float a = 0.f;
    for (int k = 0; k < K; ++k) a += xp[k] * w[k * 64 + ln];
    hs[(size_t)row * 64 + ln] = a * dis[row];
}
__global__ __launch_bounds__(256) void k_scatter(const int* __restrict__ src, const int* __restrict__ dst,
                                                 const float* __restrict__ hs, float* __restrict__ acc) {
    int ln = threadIdx.x & 63;
    int wid = (blockIdx.x * blockDim.x + threadIdx.x) >> 6;
    int nw = (gridDim.x * blockDim.x) >> 6;
    for (int e = wid; e < NE; e += nw) {
        int s = src[e], d = dst[e];
        atomicAdd(&acc[(size_t)d * 64 + ln], hs[(size_t)s * 64 + ln]);
    }
}
__global__ void k_gcn_finish(const float* __restrict__ acc, const float* __restrict__ hs,
                             const float* __restrict__ dis, const float* __restrict__ gb,
                             const float* __restrict__ bng, const float* __restrict__ bnb,
                             float* __restrict__ out) {
    int i = blockIdx.x * 256 + threadIdx.x;
    int d = i >> 6, c = i & 63;
    float rs = rsqrtf(1.0f + 1e-5f);
    float v = (acc[i] + hs[i]) * dis[d] + gb[c];
    v = v * (bng[c] * rs) + bnb[c];
    out[i] = fmaxf(v, 0.f);
}

// ---------------- fused 2-layer LSTM: all weights on-chip ----------------
// 256 blocks x 512 threads (8 waves), 32 rows/block. Wave w owns hidden cols [16w,16w+16).
// LDS: W_hh0 (128 KB, kg-major) + x1 (16 KB, chunk-swizzled h0|h1).
// Regs: layer-1 B (128 VGPR) + layer-0 dyn-tail B (16 VGPR).
__device__ __forceinline__ h8 ldx(const _Float16* x1s, int row, int chunk) {
    return *(const h8*)((const char*)x1s + row * 512 + ((chunk ^ (row & 7)) << 4));
}
__device__ __forceinline__ void wrx(_Float16* x1s, int row, int col, _Float16 v) {
    *(_Float16*)((char*)x1s + row * 512 + ((((col >> 3) ^ (row & 7))) << 4) + (col & 7) * 2) = v;
}

__global__ __launch_bounds__(512, 2) void k_lstm(const float* __restrict__ dyn,
                                                 const _Float16* __restrict__ WB0h,
                                                 const _Float16* __restrict__ TLg,
                                                 const _Float16* __restrict__ WB1,
                                                 const float* __restrict__ bias,
                                                 float* __restrict__ rnn) {
    __shared__ __align__(16) _Float16 wb0[65536];  // [kt][kg][col][8] = 128 KB
    __shared__ __align__(16) _Float16 x1s[8192];   // 32 rows x 256 cols, swizzled: cols 0-127 h0, 128-255 h1

    const int tid = threadIdx.x;
    const int wv = tid >> 6, ln = tid & 63;
    const int lr = ln & 15, kg = ln >> 4;
    const int j = wv * 16 + lr;
    const int row0 = blockIdx.x * 32;

    for (int i = tid; i < 8192; i += 512) ((v4*)wb0)[i] = ((const v4*)WB0h)[i];
    for (int i = tid; i < 8192; i += 512) x1s[i] = (_Float16)0.f;

    // layer-1 B fragments in registers (static indexing only!)
    h8 b1r[8][4];
#pragma unroll
    for (int kt = 0; kt < 8; ++kt)
#pragma unroll
        for (int q = 0; q < 4; ++q)
            b1r[kt][q] = *(const h8*)(WB1 + (size_t)kt * 16384 + (q * 128 + j) * 32 + kg * 8);
    // layer-0 dyn-tail B (k in [128,144) of reordered K; kg>=2 lanes pair with zero-A)
    h8 bt[4];
#pragma unroll
    for (int q = 0; q < 4; ++q)
        bt[q] = *(const h8*)(TLg + (q * 128 + j) * 16 + (kg & 1) * 8);

    float b0q[4], b1q[4];
#pragma unroll
    for (int q = 0; q < 4; ++q) { b0q[q] = bias[q * 128 + j]; b1q[q] = bias[512 + q * 128 + j]; }
    float c0[2][4], c1[2][4];
#pragma unroll
    for (int mt = 0; mt < 2; ++mt)
#pragma unroll
        for (int r = 0; r < 4; ++r) { c0[mt][r] = 0.f; c1[mt][r] = 0.f; }

    // dyn stage for t=0 (8 f32 per lane; kg>=2 lanes load kg&1's data, unused)
    f4 dz[2][2];
#pragma unroll
    for (int mt = 0; mt < 2; ++mt) {
        const float* p = dyn + (size_t)(row0 + mt * 16 + lr) * 512 + (kg & 1) * 8;
        dz[mt][0] = *(const f4*)p;
        dz[mt][1] = *(const f4*)(p + 4);
    }
    __syncthreads();

#pragma unroll 1
    for (int t = 0; t < 32; ++t) {
        f4 acc[2][4];
        // ===== layer 0 GEMM: K reordered = [h0(t-1) 128 | dyn_t 16 | zero-pad 16] =====
#pragma unroll
        for (int q = 0; q < 4; ++q) { f4 z = {b0q[q], b0q[q], b0q[q], b0q[q]}; acc[0][q] = z; acc[1][q] = z; }
#pragma unroll
        for (int kt = 0; kt < 4; ++kt) {
            h8 a0 = ldx(x1s, lr, kt * 4 + kg);
            h8 a1 = ldx(x1s, 16 + lr, kt * 4 + kg);
            h8 bq[4];
#pragma unroll
            for (int q = 0; q < 4; ++q)
                bq[q] = *(const h8*)(wb0 + (size_t)(((kt * 4 + kg) * 512 + q * 128 + j) * 8));
#pragma unroll
            for (int q = 0; q < 4; ++q) {
                acc[0][q] = __builtin_amdgcn_mfma_f32_16x16x32_f16(a0, bq[q], acc[0][q], 0, 0, 0);
                acc[1][q] = __builtin_amdgcn_mfma_f32_16x16x32_f16(a1, bq[q], acc[1][q], 0, 0, 0);
            }
        }
        {   // dyn tail ktile: A = dyn (kg 0,1) or zero (kg 2,3); B = bt regs
            h8 da[2];
#pragma unroll
            for (int mt = 0; mt < 2; ++mt) {
                if (kg < 2) {
#pragma unroll
                    for (int e = 0; e < 4; ++e) {
                        da[mt][e] = (_Float16)dz[mt][0][e];
                        da[mt][4 + e] = (_Float16)dz[mt][1][e];
                    }
                } else {
#pragma unroll
                    for (int e = 0; e < 8; ++e) da[mt][e] = (_Float16)0.f;
                }
            }
#pragma unroll
            for (int q = 0; q < 4; ++q) {
                acc[0][q] = __builtin_amdgcn_mfma_f32_16x16x32_f16(da[0], bt[q], acc[0][q], 0, 0, 0);
                acc[1][q] = __builtin_amdgcn_mfma_f32_16x16x32_f16(da[1], bt[q], acc[1][q], 0, 0, 0);
            }
        }
        __syncthreads();  // (a) all x1 h0-reads done
        // ===== layer 0 elementwise -> h0(t) =====
#pragma unroll
        for (int mt = 0; mt < 2; ++mt)
#pragma unroll
            for (int r = 0; r < 4; ++r) {
                float iv = acc[mt][0][r], fv = acc[mt][1][r], gv = acc[mt][2][r], ov = acc[mt][3][r];
                float c = sigm(fv) * c0[mt][r] + sigm(iv) * tanh_(gv);
                c0[mt][r] = c;
                float h = sigm(ov) * tanh_(c);
                wrx(x1s, mt * 16 + kg * 4 + r, j, (_Float16)h);
            }
        if (t < 31) {  // prefetch dyn_{t+1} (dz already consumed above)
#pragma unroll
            for (int mt = 0; mt < 2; ++mt) {
                const float* p = dyn + (size_t)(row0 + mt * 16 + lr) * 512 + (t + 1) * 16 + (kg & 1) * 8;
                dz[mt][0] = *(const f4*)p;
                dz[mt][1] = *(const f4*)(p + 4);
            }
        }
        __syncthreads();  // (b) h0(t) visible
        // ===== layer 1 GEMM: K=256 = [h0(t) | h1(t-1)], B in regs =====
#pragma unroll
        for (int q = 0; q < 4; ++q) { f4 z = {b1q[q], b1q[q], b1q[q], b1q[q]}; acc[0][q] = z; acc[1][q] = z; }
#pragma unroll
        for (int kt = 0; kt < 8; ++kt) {
            h8 a0 = ldx(x1s, lr, kt * 4 + kg);
            h8 a1 = ldx(x1s, 16 + lr, kt * 4 + kg);
#pragma unroll
            for (int q = 0; q < 4; ++q) {
                acc[0][q] = __builtin_amdgcn_mfma_f32_16x16x32_f16(a0, b1r[kt][q], acc[0][q], 0, 0, 0);
                acc[1][q] = __builtin_amdgcn_mfma_f32_16x16x32_f16(a1, b1r[kt][q], acc[1][q], 0, 0, 0);
            }
        }
        __syncthreads();  // (c) all x1 reads done
        // ===== layer 1 elementwise -> h1(t) =====
#pragma unroll
        for (int mt = 0; mt < 2; ++mt)
#pragma unroll
            for (int r = 0; r < 4; ++r) {
                float iv = acc[mt][0][r], fv = acc[mt][1][r], gv = acc[mt][2][r], ov = acc[mt][3][r];
                float c = sigm(fv) * c1[mt][r] + sigm(iv) * tanh_(gv);
                c1[mt][r] = c;
                float h = sigm(ov) * tanh_(c);
                int rr = mt * 16 + kg * 4 + r;
                if (t < 31) wrx(x1s, rr, 128 + j, (_Float16)h);
                else rnn[(size_t)(row0 + rr) * 128 + j] = h;
            }
    }
}

// ---------------- head ----------------
__global__ __launch_bounds__(256) void k_head(const float* __restrict__ gnn, const float* __restrict__ rnn,
                                              const float* __restrict__ fc1w, const float* __restrict__ fc1b,
                                              const float* __restrict__ fbng, const float* __restrict__ fbnb,
                                              const float* __restrict__ fc2w, const float* __restrict__ fc2b,
                                              const float* __restrict__ outw, const float* __restrict__ outb,
                                              float* __restrict__ out) {
    __shared__ __align__(16) float xin[32][196];
    __shared__ __align__(16) float xh2[32][132];
    __shared__ __align__(16) float xh3[32][68];
    const int tid = threadIdx.x;
    const int r0 = blockIdx.x * 32;
    for (int i = tid; i < 32 * 64; i += 256) { int r = i >> 6, c = i & 63; xin[r][c] = gnn[(size_t)(r0 + r) * 64 + c]; }
    for (int i = tid; i < 32 * 128; i += 256) { int r = i >> 7, c = i & 127; xin[r][64 + c] = rnn[(size_t)(r0 + r) * 128 + c]; }
    __syncthreads();
    const int wv = tid >> 6, ln = tid & 63, wr = wv * 8;
    const float rs = rsqrtf(1.0f + 1e-5f);
    float a[8][2];
    float b0 = fc1b[2 * ln], b1 = fc1b[2 * ln + 1];
#pragma unroll
    for (int r = 0; r < 8; ++r) { a[r][0] = b0; a[r][1] = b1; }
    for (int k = 0; k < 192; ++k) {
        v2 w = *(const v2*)&fc1w[k * 128 + 2 * ln];
#pragma unroll
        for (int r = 0; r < 8; ++r) { float x = xin[wr + r][k]; a[r][0] += x * w[0]; a[r][1] += x * w[1]; }
    }
    float s0 = fbng[2 * ln] * rs, s1 = fbng[2 * ln + 1] * rs;
    float bb0 = fbnb[2 * ln], bb1 = fbnb[2 * ln + 1];
#pragma unroll
    for (int r = 0; r < 8; ++r) {
        v2 h;
        h[0] = fmaxf(a[r][0] * s0 + bb0, 0.f);
        h[1] = fmaxf(a[r][1] * s1 + bb1, 0.f);
        *(v2*)&xh2[wr + r][2 * ln] = h;
    }
    __syncthreads();
    float a2[8];
    float b2 = fc2b[ln];
#pragma unroll
    for (int r = 0; r < 8; ++r) a2[r] = b2;
    for (int k = 0; k < 128; ++k) {
        float w = fc2w[k * 64 + ln];
#pragma unroll
        for (int r = 0; r < 8; ++r) a2[r] += xh2[wr + r][k] * w;
    }
#pragma unroll
    for (int r = 0; r < 8; ++r) xh3[wr + r][ln] = fmaxf(a2[r], 0.f);
    __syncthreads();
    if (ln < 10) {
#pragma unroll
        for (int r = 0; r < 8; ++r) {
            float a3 = outb[ln];
            for (int k = 0; k < 64; ++k) a3 += xh3[wr + r][k] * outw[k * 10 + ln];
            out[(size_t)(r0 + wr + r) * 10 + ln] = a3;
        }
    }
}

extern "C" void kernel_launch(void* const* d_in, const int* in_sizes, int n_in,
                              void* d_out, int out_size, void* d_ws, size_t ws_size,
                              hipStream_t stream) {
    const float* dyn  = (const float*)d_in[0];
    const float* xs   = (const float*)d_in[1];
    const int*   ei   = (const int*)d_in[2];
    const float* g1w  = (const float*)d_in[3];
    const float* g1b  = (const float*)d_in[4];
    const float* g2w  = (const float*)d_in[5];
    const float* g2b  = (const float*)d_in[6];
    const float* bn1g = (const float*)d_in[7];
    const float* bn1b = (const float*)d_in[8];
    const float* bn2g = (const float*)d_in[9];
    const float* bn2b = (const float*)d_in[10];
    const float* wih0 = (const float*)d_in[11];
    const float* whh0 = (const float*)d_in[12];
    const float* bih0 = (const float*)d_in[13];
    const float* bhh0 = (const float*)d_in[14];
    const float* wih1 = (const float*)d_in[15];
    const float* whh1 = (const float*)d_in[16];
    const float* bih1 = (const float*)d_in[17];
    const float* bhh1 = (const float*)d_in[18];
    const float* fc1w = (const float*)d_in[19];
    const float* fc1b = (const float*)d_in[20];
    const float* fbng = (const float*)d_in[21];
    const float* fbnb = (const float*)d_in[22];
    const float* fc2w = (const float*)d_in[23];
    const float* fc2b = (const float*)d_in[24];
    const float* outw = (const float*)d_in[25];
    const float* outb = (const float*)d_in[26];
    float* out = (float*)d_out;

    _Float16* WB0h = (_Float16*)d_ws;         // 65536
    _Float16* TLg  = WB0h + 65536;            // 8192
    _Float16* WB1  = TLg + 8192;              // 131072   (f16 region = 409600 B)
    float* fbase = (float*)((char*)d_ws + 409600);
    float* bias = fbase;                      // 1024
    float* dis  = fbase + 1024;               // 8192
    float* hs   = fbase + 9216;               // 524288
    float* agg  = fbase + 533504;             // 524288
    float* y1   = fbase + 1057792;            // 524288
    float* gnn  = fbase + 1582080;            // 524288
    float* rnn  = fbase + 2106368;            // 1048576

    const int* srcp = ei;
    const int* dstp = ei + NE;

    k_prep<<<804, 256, 0, stream>>>(wih0, whh0, bih0, bhh0, wih1, whh1, bih1, bhh1, WB0h, TLg, WB1, bias);
    k_deg_init<<<32, 256, 0, stream>>>(dis);
    k_deg_count<<<1024, 256, 0, stream>>>(dstp, dis);
    k_dis<<<32, 256, 0, stream>>>(dis);
    k_gcn_gemm<<<2048, 256, 0, stream>>>(xs, g1w, dis, hs, 128);
    hipMemsetAsync(agg, 0, (size_t)524288 * sizeof(float), stream);
    k_scatter<<<2048, 256, 0, stream>>>(srcp, dstp, hs, agg);
    k_gcn_finish<<<2048, 256, 0, stream>>>(agg, hs, dis, g1b, bn1g, bn1b, y1);
    k_gcn_gemm<<<2048, 256, 0, stream>>>(y1, g2w, dis, hs, 64);
    hipMemsetAsync(agg, 0, (size_t)524288 * sizeof(float), stream);
    k_scatter<<<2048, 256, 0, stream>>>(srcp, dstp, hs, agg);
    k_gcn_finish<<<2048, 256, 0, stream>>>(agg, hs, dis, g2b, bn2g, bn2b, gnn);
    k_lstm<<<256, 512, 0, stream>>>(dyn, WB0h, TLg, WB1, bias, rnn);
    k_head<<<256, 256, 0, stream>>>(gnn, rnn, fc1w, fc1b, fbng, fbnb, fc2w, fc2b, outw, outb, out);
}

// Round 4
// 452.006 us; speedup vs baseline: 4.6322x; 1.2295x over previous
//
#include <hip/hip_runtime.h>
#include <hip/hip_bf16.h>

#define NN 8192
#define NE 262144

typedef float v2 __attribute__((ext_vector_type(2)));
typedef float v4 __attribute__((ext_vector_type(4)));
typedef float f4 __attribute__((ext_vector_type(4)));
typedef _Float16 h8 __attribute__((ext_vector_type(8)));
typedef _Float16 h4 __attribute__((ext_vector_type(4)));

__device__ __forceinline__ float rcp_(float x) { return __builtin_amdgcn_rcpf(x); }
__device__ __forceinline__ float sigm(float x) { return rcp_(1.0f + __expf(-x)); }
__device__ __forceinline__ float tanh_(float x) { return 1.0f - 2.0f * rcp_(__expf(2.0f * x) + 1.0f); }

// ---------------- prep ----------------
// WB0h[4][4][512][8] f16 : layer0 W_hh0, ((kt*4+kg)*512+col)*8+idx = whh0[col][kt*32+kg*8+idx]
// TL[512][16]        f16 : layer0 W_ih0 transposed
// WB1[8][512][32]    f16 : layer1, K=256 (k<128: w_ih1; else w_hh1), col-major per ktile
// bias[0:512]=b_ih0+b_hh0 ; bias[512:1024]=b_ih1+b_hh1 (fp32)
__global__ void k_prep(const float* __restrict__ wih0, const float* __restrict__ whh0,
                       const float* __restrict__ bih0, const float* __restrict__ bhh0,
                       const float* __restrict__ wih1, const float* __restrict__ whh1,
                       const float* __restrict__ bih1, const float* __restrict__ bhh1,
                       _Float16* __restrict__ WB0h, _Float16* __restrict__ TLg,
                       _Float16* __restrict__ WB1, float* __restrict__ bias) {
    int i = blockIdx.x * 256 + threadIdx.x;
    if (i < 65536) {
        int idx = i & 7, col = (i >> 3) & 511, kgq = (i >> 12) & 3, kt = i >> 14;
        int kh = kt * 32 + kgq * 8 + idx;
        WB0h[i] = (_Float16)whh0[col * 128 + kh];
    } else if (i < 73728) {
        int m = i - 65536;
        int kd = m & 15, g = m >> 4;
        TLg[m] = (_Float16)wih0[g * 16 + kd];
    } else if (i < 204800) {
        int m = i - 73728;
        int kt = m >> 14, rem = m & 16383, g = rem >> 5, kk = rem & 31, k = kt * 32 + kk;
        WB1[m] = (_Float16)((k < 128) ? wih1[g * 128 + k] : whh1[g * 128 + (k - 128)]);
    } else if (i < 205824) {
        int g = i - 204800;
        bias[g] = (g < 512) ? (bih0[g] + bhh0[g]) : (bih1[g - 512] + bhh1[g - 512]);
    }
}
__global__ void k_cvt_dyn(const float* __restrict__ dyn, _Float16* __restrict__ dyn16) {
    int i = blockIdx.x * 256 + threadIdx.x;  // x4 elems
    f4 v = *(const f4*)(dyn + (size_t)i * 4);
    h4 o = {(_Float16)v[0], (_Float16)v[1], (_Float16)v[2], (_Float16)v[3]};
    *(h4*)(dyn16 + (size_t)i * 4) = o;
}

// ---------------- GCN: CSR build + gather ----------------
__global__ void k_deg_count(const int* __restrict__ dst, int* __restrict__ cnt) {
    int i = blockIdx.x * 256 + threadIdx.x;
    if (i < NE) atomicAdd(&cnt[dst[i]], 1);
}
__global__ __launch_bounds__(1024) void k_scan(const int* __restrict__ cnt, int* __restrict__ rowstart,
                                               float* __restrict__ dis) {
    __shared__ int part[1024];
    int t = threadIdx.x;
    int base = t * 8, s = 0, loc[8];
#pragma unroll
    for (int i = 0; i < 8; ++i) { loc[i] = s; s += cnt[base + i]; }
    part[t] = s;
    __syncthreads();
    for (int off = 1; off < 1024; off <<= 1) {
        int v = part[t];
        int add = (t >= off) ? part[t - off] : 0;
        __syncthreads();
        part[t] = v + add;
        __syncthreads();
    }
    int pre = (t == 0) ? 0 : part[t - 1];
#pragma unroll
    for (int i = 0; i < 8; ++i) {
        rowstart[base + i] = pre + loc[i];
        dis[base + i] = rsqrtf((float)(cnt[base + i] + 1));  // +1 self-loop
    }
    if (t == 1023) rowstart[8192] = NE;
}
__global__ void k_fill(const int* __restrict__ src, const int* __restrict__ dst,
                       const int* __restrict__ rowstart, int* __restrict__ cursor,
                       int* __restrict__ srcidx) {
    int e = blockIdx.x * 256 + threadIdx.x;
    if (e < NE) {
        int d = dst[e];
        int pos = rowstart[d] + atomicAdd(&cursor[d], 1);
        srcidx[pos] = src[e];
    }
}
// hs[r][c] = (x@W)[r][c] * dis[r]
__global__ __launch_bounds__(256) void k_gcn_gemm(const float* __restrict__ in, const float* __restrict__ w,
                                                  const float* __restrict__ dis, float* __restrict__ hs, int K) {
    int wv = threadIdx.x >> 6, ln = threadIdx.x & 63;
    int row = blockIdx.x * 4 + wv;
    const float* xp = in + (size_t)row * K;
    float a = 0.f;
    for (int k = 0; k < K; ++k) a += xp[k] * w[k * 64 + ln];
    hs[(size_t)row * 64 + ln] = a * dis[row];
}
// out = relu( ((sum_in hs[s]) + hs[d]) * dis[d] + b ) with BN fused; one wave per node
__global__ __launch_bounds__(256) void k_gather(const float* __restrict__ hs, const int* __restrict__ srcidx,
                                                const int* __restrict__ rowstart, const float* __restrict__ dis,
                                                const float* __restrict__ gb, const float* __restrict__ bng,
                                                const float* __restrict__ bnb, float* __restrict__ out) {
    int ln = threadIdx.x & 63;
    int d = (blockIdx.x * 256 + threadIdx.x) >> 6;
    float acc = hs[(size_t)d * 64 + ln];  // self-loop
    int b = rowstart[d], e = rowstart[d + 1];
    int i = b;
    for (; i + 4 <= e; i += 4) {
        int s0 = srcidx[i], s1 = srcidx[i + 1], s2 = srcidx[i + 2], s3 = srcidx[i + 3];
        acc += hs[(size_t)s0 * 64 + ln];
        acc += hs[(size_t)s1 * 64 + ln];
        acc += hs[(size_t)s2 * 64 + ln];
        acc += hs[(size_t)s3 * 64 + ln];
    }
    for (; i < e; ++i) acc += hs[(size_t)srcidx[i] * 64 + ln];
    float rs = rsqrtf(1.0f + 1e-5f);
    float v = acc * dis[d] + gb[ln];
    v = v * (bng[ln] * rs) + bnb[ln];
    out[(size_t)d * 64 + ln] = fmaxf(v, 0.f);
}

// ---------------- fused 2-layer LSTM: all weights on-chip, 1 barrier/step ----------------
// 256 blocks x 512 threads (8 waves), 32 rows/block. Wave w owns hidden cols [16w,16w+16).
// LDS: W_hh0 (128 KB, kg-major) + xs (32 KB: 2 bufs x 32 rows x [h0|h1]), exactly 160 KB.
__device__ __forceinline__ h8 ldx(const _Float16* xs, int buf, int row, int chunk) {
    return *(const h8*)((const char*)xs + buf * 16384 + row * 512 + ((chunk ^ (row & 7)) << 4));
}
__device__ __forceinline__ void wrx(_Float16* xs, int buf, int row, int col, _Float16 v) {
    *(_Float16*)((char*)xs + buf * 16384 + row * 512 + ((((col >> 3) ^ (row & 7))) << 4) + (col & 7) * 2) = v;
}

__global__ __launch_bounds__(512, 2) void k_lstm(const _Float16* __restrict__ dyn16,
                                                 const _Float16* __restrict__ WB0h,
                                                 const _Float16* __restrict__ TLg,
                                                 const _Float16* __restrict__ WB1,
                                                 const float* __restrict__ bias,
                                                 float* __restrict__ rnn) {
    __shared__ __align__(16) _Float16 wb0[65536];  // 128 KB
    __shared__ __align__(16) _Float16 xs[16384];   // 2 x 32 x 256, swizzled; cols 0-127 h0, 128-255 h1

    const int tid = threadIdx.x;
    const int wv = tid >> 6, ln = tid & 63;
    const int lr = ln & 15, kg = ln >> 4;
    const int j = wv * 16 + lr;
    const int row0 = blockIdx.x * 32;

    for (int i = tid; i < 8192; i += 512) ((v4*)wb0)[i] = ((const v4*)WB0h)[i];
    for (int i = tid; i < 16384; i += 512) xs[i] = (_Float16)0.f;

    // layer-1 B fragments in registers/AGPRs (static indexing only)
    h8 b1r[8][4];
#pragma unroll
    for (int kt = 0; kt < 8; ++kt)
#pragma unroll
        for (int q = 0; q < 4; ++q)
            b1r[kt][q] = *(const h8*)(WB1 + (size_t)kt * 16384 + (q * 128 + j) * 32 + kg * 8);
    // layer-0 dyn-tail B (kg>=2 lanes pair with zero-A)
    h8 bt[4];
#pragma unroll
    for (int q = 0; q < 4; ++q)
        bt[q] = *(const h8*)(TLg + (q * 128 + j) * 16 + (kg & 1) * 8);

    float b0q[4], b1q[4];
#pragma unroll
    for (int q = 0; q < 4; ++q) { b0q[q] = bias[q * 128 + j]; b1q[q] = bias[512 + q * 128 + j]; }
    float c0[2][4], c1[2][4];
#pragma unroll
    for (int mt = 0; mt < 2; ++mt)
#pragma unroll
        for (int r = 0; r < 4; ++r) { c0[mt][r] = 0.f; c1[mt][r] = 0.f; }

    h8 dreg[2];
#pragma unroll
    for (int mt = 0; mt < 2; ++mt)
#pragma unroll
        for (int e = 0; e < 8; ++e) dreg[mt][e] = (_Float16)0.f;
    if (kg < 2) {
#pragma unroll
        for (int mt = 0; mt < 2; ++mt)
            dreg[mt] = *(const h8*)(dyn16 + (size_t)(row0 + mt * 16 + lr) * 512 + (kg & 1) * 8);
    }
    __syncthreads();

#pragma unroll 1
    for (int t = 0; t < 32; ++t) {
        const int cur = t & 1, old = cur ^ 1;
        f4 acc[2][4];
        // ===== G0: layer-0 GEMM, K = [h0(t-1) 128 | dyn_t 16 | pad 16] =====
#pragma unroll
        for (int q = 0; q < 4; ++q) { f4 z = {b0q[q], b0q[q], b0q[q], b0q[q]}; acc[0][q] = z; acc[1][q] = z; }
#pragma unroll
        for (int kt = 0; kt < 4; ++kt) {
            h8 a0 = ldx(xs, old, lr, kt * 4 + kg);
            h8 a1 = ldx(xs, old, 16 + lr, kt * 4 + kg);
            h8 bq[4];
#pragma unroll
            for (int q = 0; q < 4; ++q)
                bq[q] = *(const h8*)(wb0 + (size_t)(((kt * 4 + kg) * 512 + q * 128 + j) * 8));
#pragma unroll
            for (int q = 0; q < 4; ++q) {
                acc[0][q] = __builtin_amdgcn_mfma_f32_16x16x32_f16(a0, bq[q], acc[0][q], 0, 0, 0);
                acc[1][q] = __builtin_amdgcn_mfma_f32_16x16x32_f16(a1, bq[q], acc[1][q], 0, 0, 0);
            }
        }
#pragma unroll
        for (int q = 0; q < 4; ++q) {
            acc[0][q] = __builtin_amdgcn_mfma_f32_16x16x32_f16(dreg[0], bt[q], acc[0][q], 0, 0, 0);
            acc[1][q] = __builtin_amdgcn_mfma_f32_16x16x32_f16(dreg[1], bt[q], acc[1][q], 0, 0, 0);
        }
        // ===== EW0 -> h0(t) into buf cur =====
#pragma unroll
        for (int mt = 0; mt < 2; ++mt)
#pragma unroll
            for (int r = 0; r < 4; ++r) {
                float iv = acc[mt][0][r], fv = acc[mt][1][r], gv = acc[mt][2][r], ov = acc[mt][3][r];
                float c = sigm(fv) * c0[mt][r] + sigm(iv) * tanh_(gv);
                c0[mt][r] = c;
                float h = sigm(ov) * tanh_(c);
                wrx(xs, cur, mt * 16 + kg * 4 + r, j, (_Float16)h);
            }
        if (t < 31 && kg < 2) {  // prefetch dyn_{t+1}
#pragma unroll
            for (int mt = 0; mt < 2; ++mt)
                dreg[mt] = *(const h8*)(dyn16 + (size_t)(row0 + mt * 16 + lr) * 512 + (t + 1) * 16 + (kg & 1) * 8);
        }
        __syncthreads();  // the ONE barrier: h0(t) visible
        // ===== G1: layer-1 GEMM, K=256 = [h0(t) buf cur | h1(t-1) buf old] =====
#pragma unroll
        for (int q = 0; q < 4; ++q) { f4 z = {b1q[q], b1q[q], b1q[q], b1q[q]}; acc[0][q] = z; acc[1][q] = z; }
#pragma unroll
        for (int kt = 0; kt < 8; ++kt) {
            const int bufA = (kt < 4) ? cur : old;
            const int ch = (kt < 4) ? (kt * 4 + kg) : (16 + (kt - 4) * 4 + kg);
            h8 a0 = ldx(xs, bufA, lr, ch);
            h8 a1 = ldx(xs, bufA, 16 + lr, ch);
#pragma unroll
            for (int q = 0; q < 4; ++q) {
                acc[0][q] = __builtin_amdgcn_mfma_f32_16x16x32_f16(a0, b1r[kt][q], acc[0][q], 0, 0, 0);
                acc[1][q] = __builtin_amdgcn_mfma_f32_16x16x32_f16(a1, b1r[kt][q], acc[1][q], 0, 0, 0);
            }
        }
        // ===== EW1 -> h1(t) into buf cur =====
#pragma unroll
        for (int mt = 0; mt < 2; ++mt)
#pragma unroll
            for (int r = 0; r < 4; ++r) {
                float iv = acc[mt][0][r], fv = acc[mt][1][r], gv = acc[mt][2][r], ov = acc[mt][3][r];
                float c = sigm(fv) * c1[mt][r] + sigm(iv) * tanh_(gv);
                c1[mt][r] = c;
                float h = sigm(ov) * tanh_(c);
                int rr = mt * 16 + kg * 4 + r;
                if (t < 31) wrx(xs, cur, rr, 128 + j, (_Float16)h);
                else rnn[(size_t)(row0 + rr) * 128 + j] = h;
            }
    }
}

// ---------------- head ----------------
__global__ __launch_bounds__(256) void k_head(const float* __restrict__ gnn, const float* __restrict__ rnn,
                                              const float* __restrict__ fc1w, const float* __restrict__ fc1b,
                                              const float* __restrict__ fbng, const float* __restrict__ fbnb,
                                              const float* __restrict__ fc2w, const float* __restrict__ fc2b,
                                              const float* __restrict__ outw, const float* __restrict__ outb,
                                              float* __restrict__ out) {
    __shared__ __align__(16) float xin[32][196];
    __shared__ __align__(16) float xh2[32][132];
    __shared__ __align__(16) float xh3[32][68];
    const int tid = threadIdx.x;
    const int r0 = blockIdx.x * 32;
    for (int i = tid; i < 32 * 64; i += 256) { int r = i >> 6, c = i & 63; xin[r][c] = gnn[(size_t)(r0 + r) * 64 + c]; }
    for (int i = tid; i < 32 * 128; i += 256) { int r = i >> 7, c = i & 127; xin[r][64 + c] = rnn[(size_t)(r0 + r) * 128 + c]; }
    __syncthreads();
    const int wv = tid >> 6, ln = tid & 63, wr = wv * 8;
    const float rs = rsqrtf(1.0f + 1e-5f);
    float a[8][2];
    float b0 = fc1b[2 * ln], b1 = fc1b[2 * ln + 1];
#pragma unroll
    for (int r = 0; r < 8; ++r) { a[r][0] = b0; a[r][1] = b1; }
    for (int k = 0; k < 192; ++k) {
        v2 w = *(const v2*)&fc1w[k * 128 + 2 * ln];
#pragma unroll
        for (int r = 0; r < 8; ++r) { float x = xin[wr + r][k]; a[r][0] += x * w[0]; a[r][1] += x * w[1]; }
    }
    float s0 = fbng[2 * ln] * rs, s1 = fbng[2 * ln + 1] * rs;
    float bb0 = fbnb[2 * ln], bb1 = fbnb[2 * ln + 1];
#pragma unroll
    for (int r = 0; r < 8; ++r) {
        v2 h;
        h[0] = fmaxf(a[r][0] * s0 + bb0, 0.f);
        h[1] = fmaxf(a[r][1] * s1 + bb1, 0.f);
        *(v2*)&xh2[wr + r][2 * ln] = h;
    }
    __syncthreads();
    float a2[8];
    float b2 = fc2b[ln];
#pragma unroll
    for (int r = 0; r < 8; ++r) a2[r] = b2;
    for (int k = 0; k < 128; ++k) {
        float w = fc2w[k * 64 + ln];
#pragma unroll
        for (int r = 0; r < 8; ++r) a2[r] += xh2[wr + r][k] * w;
    }
#pragma unroll
    for (int r = 0; r < 8; ++r) xh3[wr + r][ln] = fmaxf(a2[r], 0.f);
    __syncthreads();
    if (ln < 10) {
#pragma unroll
        for (int r = 0; r < 8; ++r) {
            float a3 = outb[ln];
            for (int k = 0; k < 64; ++k) a3 += xh3[wr + r][k] * outw[k * 10 + ln];
            out[(size_t)(r0 + wr + r) * 10 + ln] = a3;
        }
    }
}

extern "C" void kernel_launch(void* const* d_in, const int* in_sizes, int n_in,
                              void* d_out, int out_size, void* d_ws, size_t ws_size,
                              hipStream_t stream) {
    const float* dyn  = (const float*)d_in[0];
    const float* xs_  = (const float*)d_in[1];
    const int*   ei   = (const int*)d_in[2];
    const float* g1w  = (const float*)d_in[3];
    const float* g1b  = (const float*)d_in[4];
    const float* g2w  = (const float*)d_in[5];
    const float* g2b  = (const float*)d_in[6];
    const float* bn1g = (const float*)d_in[7];
    const float* bn1b = (const float*)d_in[8];
    const float* bn2g = (const float*)d_in[9];
    const float* bn2b = (const float*)d_in[10];
    const float* wih0 = (const float*)d_in[11];
    const float* whh0 = (const float*)d_in[12];
    const float* bih0 = (const float*)d_in[13];
    const float* bhh0 = (const float*)d_in[14];
    const float* wih1 = (const float*)d_in[15];
    const float* whh1 = (const float*)d_in[16];
    const float* bih1 = (const float*)d_in[17];
    const float* bhh1 = (const float*)d_in[18];
    const float* fc1w = (const float*)d_in[19];
    const float* fc1b = (const float*)d_in[20];
    const float* fbng = (const float*)d_in[21];
    const float* fbnb = (const float*)d_in[22];
    const float* fc2w = (const float*)d_in[23];
    const float* fc2b = (const float*)d_in[24];
    const float* outw = (const float*)d_in[25];
    const float* outb = (const float*)d_in[26];
    float* out = (float*)d_out;

    char* ws = (char*)d_ws;
    _Float16* WB0h  = (_Float16*)(ws + 0);         // 65536 h16
    _Float16* TLg   = (_Float16*)(ws + 131072);    // 8192 h16
    _Float16* WB1   = (_Float16*)(ws + 147456);    // 131072 h16
    _Float16* dyn16 = (_Float16*)(ws + 409600);    // 4194304 h16
    float* fbase = (float*)(ws + 8798208);
    float* bias = fbase;                           // 1024
    float* dis  = fbase + 1024;                    // 8192
    float* hs   = fbase + 9216;                    // 524288
    float* y1   = fbase + 533504;                  // 524288
    float* gnn  = fbase + 1057792;                 // 524288
    float* rnn  = fbase + 1582080;                 // 1048576
    int* ibase   = (int*)(ws + 19320832);
    int* cnt     = ibase;                          // 8192
    int* cursor  = ibase + 8192;                   // 8192 (adjacent to cnt for one memset)
    int* rowstart= ibase + 16384;                  // 8193
    int* srcidx  = ibase + 24592;                  // 262144 (16B-aligned start)

    const int* srcp = ei;
    const int* dstp = ei + NE;

    // prep
    k_prep<<<804, 256, 0, stream>>>(wih0, whh0, bih0, bhh0, wih1, whh1, bih1, bhh1, WB0h, TLg, WB1, bias);
    k_cvt_dyn<<<4096, 256, 0, stream>>>(dyn, dyn16);
    // CSR build
    hipMemsetAsync(cnt, 0, 2 * 8192 * sizeof(int), stream);  // cnt + cursor
    k_deg_count<<<1024, 256, 0, stream>>>(dstp, cnt);
    k_scan<<<1, 1024, 0, stream>>>(cnt, rowstart, dis);
    k_fill<<<1024, 256, 0, stream>>>(srcp, dstp, rowstart, cursor, srcidx);
    // GCN layer 1
    k_gcn_gemm<<<2048, 256, 0, stream>>>(xs_, g1w, dis, hs, 128);
    k_gather<<<2048, 256, 0, stream>>>(hs, srcidx, rowstart, dis, g1b, bn1g, bn1b, y1);
    // GCN layer 2
    k_gcn_gemm<<<2048, 256, 0, stream>>>(y1, g2w, dis, hs, 64);
    k_gather<<<2048, 256, 0, stream>>>(hs, srcidx, rowstart, dis, g2b, bn2g, bn2b, gnn);
    // LSTM + head
    k_lstm<<<256, 512, 0, stream>>>(dyn16, WB0h, TLg, WB1, bias, rnn);
    k_head<<<256, 256, 0, stream>>>(gnn, rnn, fc1w, fc1b, fbng, fbnb, fc2w, fc2b, outw, outb, out);
}

// Round 5
// 295.258 us; speedup vs baseline: 7.0914x; 1.5309x over previous
//
#include <hip/hip_runtime.h>
#include <hip/hip_bf16.h>

#define NN 8192
#define NE 262144

typedef float v2 __attribute__((ext_vector_type(2)));
typedef float v4 __attribute__((ext_vector_type(4)));
typedef float f4 __attribute__((ext_vector_type(4)));
typedef _Float16 h8 __attribute__((ext_vector_type(8)));
typedef _Float16 h4 __attribute__((ext_vector_type(4)));

__device__ __forceinline__ float rcp_(float x) { return __builtin_amdgcn_rcpf(x); }
__device__ __forceinline__ float sigm(float x) { return rcp_(1.0f + __expf(-x)); }
__device__ __forceinline__ float tanh_(float x) { return 1.0f - 2.0f * rcp_(__expf(2.0f * x) + 1.0f); }

// ---------------- prep ----------------
__global__ void k_prep(const float* __restrict__ wih0, const float* __restrict__ whh0,
                       const float* __restrict__ bih0, const float* __restrict__ bhh0,
                       const float* __restrict__ wih1, const float* __restrict__ whh1,
                       const float* __restrict__ bih1, const float* __restrict__ bhh1,
                       _Float16* __restrict__ WB0h, _Float16* __restrict__ TLg,
                       _Float16* __restrict__ WB1, float* __restrict__ bias) {
    int i = blockIdx.x * 256 + threadIdx.x;
    if (i < 65536) {
        int idx = i & 7, col = (i >> 3) & 511, kgq = (i >> 12) & 3, kt = i >> 14;
        int kh = kt * 32 + kgq * 8 + idx;
        WB0h[i] = (_Float16)whh0[col * 128 + kh];
    } else if (i < 73728) {
        int m = i - 65536;
        int kd = m & 15, g = m >> 4;
        TLg[m] = (_Float16)wih0[g * 16 + kd];
    } else if (i < 204800) {
        int m = i - 73728;
        int kt = m >> 14, rem = m & 16383, g = rem >> 5, kk = rem & 31, k = kt * 32 + kk;
        WB1[m] = (_Float16)((k < 128) ? wih1[g * 128 + k] : whh1[g * 128 + (k - 128)]);
    } else if (i < 205824) {
        int g = i - 204800;
        bias[g] = (g < 512) ? (bih0[g] + bhh0[g]) : (bih1[g - 512] + bhh1[g - 512]);
    }
}
__global__ void k_cvt_dyn(const float* __restrict__ dyn, _Float16* __restrict__ dyn16) {
    int i = blockIdx.x * 256 + threadIdx.x;
    f4 v = *(const f4*)(dyn + (size_t)i * 4);
    h4 o = {(_Float16)v[0], (_Float16)v[1], (_Float16)v[2], (_Float16)v[3]};
    *(h4*)(dyn16 + (size_t)i * 4) = o;
}

// ---------------- GCN: CSR build + gather ----------------
__global__ void k_deg_count(const int* __restrict__ dst, int* __restrict__ cnt) {
    int i = blockIdx.x * 256 + threadIdx.x;
    if (i < NE) atomicAdd(&cnt[dst[i]], 1);
}
__global__ __launch_bounds__(1024) void k_scan(const int* __restrict__ cnt, int* __restrict__ rowstart,
                                               float* __restrict__ dis) {
    __shared__ int part[1024];
    int t = threadIdx.x;
    int base = t * 8, s = 0, loc[8];
#pragma unroll
    for (int i = 0; i < 8; ++i) { loc[i] = s; s += cnt[base + i]; }
    part[t] = s;
    __syncthreads();
    for (int off = 1; off < 1024; off <<= 1) {
        int v = part[t];
        int add = (t >= off) ? part[t - off] : 0;
        __syncthreads();
        part[t] = v + add;
        __syncthreads();
    }
    int pre = (t == 0) ? 0 : part[t - 1];
#pragma unroll
    for (int i = 0; i < 8; ++i) {
        rowstart[base + i] = pre + loc[i];
        dis[base + i] = rsqrtf((float)(cnt[base + i] + 1));
    }
    if (t == 1023) rowstart[8192] = NE;
}
__global__ void k_fill(const int* __restrict__ src, const int* __restrict__ dst,
                       const int* __restrict__ rowstart, int* __restrict__ cursor,
                       int* __restrict__ srcidx) {
    int e = blockIdx.x * 256 + threadIdx.x;
    if (e < NE) {
        int d = dst[e];
        int pos = rowstart[d] + atomicAdd(&cursor[d], 1);
        srcidx[pos] = src[e];
    }
}
__global__ __launch_bounds__(256) void k_gcn_gemm(const float* __restrict__ in, const float* __restrict__ w,
                                                  const float* __restrict__ dis, float* __restrict__ hs, int K) {
    int wv = threadIdx.x >> 6, ln = threadIdx.x & 63;
    int row = blockIdx.x * 4 + wv;
    const float* xp = in + (size_t)row * K;
    float a = 0.f;
#pragma unroll 4
    for (int k = 0; k < K; ++k) a += xp[k] * w[k * 64 + ln];
    hs[(size_t)row * 64 + ln] = a * dis[row];
}
__global__ __launch_bounds__(256) void k_gather(const float* __restrict__ hs, const int* __restrict__ srcidx,
                                                const int* __restrict__ rowstart, const float* __restrict__ dis,
                                                const float* __restrict__ gb, const float* __restrict__ bng,
                                                const float* __restrict__ bnb, float* __restrict__ out) {
    int ln = threadIdx.x & 63;
    int d = (blockIdx.x * 256 + threadIdx.x) >> 6;
    float acc = hs[(size_t)d * 64 + ln];
    int b = rowstart[d], e = rowstart[d + 1];
    int i = b;
    for (; i + 4 <= e; i += 4) {
        int s0 = srcidx[i], s1 = srcidx[i + 1], s2 = srcidx[i + 2], s3 = srcidx[i + 3];
        acc += hs[(size_t)s0 * 64 + ln];
        acc += hs[(size_t)s1 * 64 + ln];
        acc += hs[(size_t)s2 * 64 + ln];
        acc += hs[(size_t)s3 * 64 + ln];
    }
    for (; i < e; ++i) acc += hs[(size_t)srcidx[i] * 64 + ln];
    float rs = rsqrtf(1.0f + 1e-5f);
    float v = acc * dis[d] + gb[ln];
    v = v * (bng[ln] * rs) + bnb[ln];
    out[(size_t)d * 64 + ln] = fmaxf(v, 0.f);
}

// ---------------- fused 2-layer LSTM: rotated loop, 1 barrier/step ----------------
// 256 blocks x 512 threads (8 waves), 32 rows/block. Wave w owns hidden cols [16w,16w+16).
// Between barriers: {G1(i), EW1(i), G0(i+1), EW0(i+1)} contiguous -> scheduler can
// overlap MFMA / VALU / TRANS / LDS pipes across sub-phases.
__device__ __forceinline__ h8 ldx(const _Float16* xs, int buf, int row, int chunk) {
    return *(const h8*)((const char*)xs + buf * 16384 + row * 512 + ((chunk ^ (row & 7)) << 4));
}
__device__ __forceinline__ void wrx(_Float16* xs, int buf, int row, int col, _Float16 v) {
    *(_Float16*)((char*)xs + buf * 16384 + row * 512 + ((((col >> 3) ^ (row & 7))) << 4) + (col & 7) * 2) = v;
}

__global__ __launch_bounds__(512, 2) void k_lstm(const _Float16* __restrict__ dyn16,
                                                 const _Float16* __restrict__ WB0h,
                                                 const _Float16* __restrict__ TLg,
                                                 const _Float16* __restrict__ WB1,
                                                 const float* __restrict__ bias,
                                                 float* __restrict__ rnn) {
    __shared__ __align__(16) _Float16 wb0[65536];  // W_hh0, 128 KB
    __shared__ __align__(16) _Float16 xs[16384];   // 2 bufs x 32 rows x [h0|h1], swizzled

    const int tid = threadIdx.x;
    const int wv = tid >> 6, ln = tid & 63;
    const int lr = ln & 15, kg = ln >> 4;
    const int j = wv * 16 + lr;
    const int row0 = blockIdx.x * 32;

    for (int i = tid; i < 8192; i += 512) ((v4*)wb0)[i] = ((const v4*)WB0h)[i];
    for (int i = tid; i < 16384; i += 512) xs[i] = (_Float16)0.f;

    h8 b1r[8][4];
#pragma unroll
    for (int kt = 0; kt < 8; ++kt)
#pragma unroll
        for (int q = 0; q < 4; ++q)
            b1r[kt][q] = *(const h8*)(WB1 + (size_t)kt * 16384 + (q * 128 + j) * 32 + kg * 8);
    h8 bt[4];
#pragma unroll
    for (int q = 0; q < 4; ++q)
        bt[q] = *(const h8*)(TLg + (q * 128 + j) * 16 + (kg & 1) * 8);

    float b0q[4], b1q[4];
#pragma unroll
    for (int q = 0; q < 4; ++q) { b0q[q] = bias[q * 128 + j]; b1q[q] = bias[512 + q * 128 + j]; }
    float c0[2][4], c1[2][4];
#pragma unroll
    for (int mt = 0; mt < 2; ++mt)
#pragma unroll
        for (int r = 0; r < 4; ++r) { c0[mt][r] = 0.f; c1[mt][r] = 0.f; }

    h8 dreg[2];
#pragma unroll
    for (int mt = 0; mt < 2; ++mt)
#pragma unroll
        for (int e = 0; e < 8; ++e) dreg[mt][e] = (_Float16)0.f;
    if (kg < 2) {
#pragma unroll
        for (int mt = 0; mt < 2; ++mt)
            dreg[mt] = *(const h8*)(dyn16 + (size_t)(row0 + mt * 16 + lr) * 512 + (kg & 1) * 8);
    }
    __syncthreads();  // wb0 + xs zero init visible

    // ===== prologue: step 0, layer 0. h0(-1)=0 -> LDS GEMM contributes 0, only dyn tail =====
    {
        f4 acc[2][4];
#pragma unroll
        for (int q = 0; q < 4; ++q) { f4 z = {b0q[q], b0q[q], b0q[q], b0q[q]}; acc[0][q] = z; acc[1][q] = z; }
#pragma unroll
        for (int q = 0; q < 4; ++q) {
            acc[0][q] = __builtin_amdgcn_mfma_f32_16x16x32_f16(dreg[0], bt[q], acc[0][q], 0, 0, 0);
            acc[1][q] = __builtin_amdgcn_mfma_f32_16x16x32_f16(dreg[1], bt[q], acc[1][q], 0, 0, 0);
        }
#pragma unroll
        for (int mt = 0; mt < 2; ++mt)
#pragma unroll
            for (int r = 0; r < 4; ++r) {
                float iv = acc[mt][0][r], fv = acc[mt][1][r], gv = acc[mt][2][r], ov = acc[mt][3][r];
                float c = sigm(fv) * c0[mt][r] + sigm(iv) * tanh_(gv);
                c0[mt][r] = c;
                wrx(xs, 0, mt * 16 + kg * 4 + r, j, (_Float16)(sigm(ov) * tanh_(c)));
            }
        if (kg < 2) {  // dreg <- dyn(1)
#pragma unroll
            for (int mt = 0; mt < 2; ++mt)
                dreg[mt] = *(const h8*)(dyn16 + (size_t)(row0 + mt * 16 + lr) * 512 + 16 + (kg & 1) * 8);
        }
    }

#pragma unroll 1
    for (int i = 0; i < 31; ++i) {
        const int cur = i & 1, old = cur ^ 1;
        __syncthreads();  // h0(i) visible
        f4 acc[2][4];
        // ===== G1(i): K=256 = [h0(i) buf cur | h1(i-1) buf old], B in regs =====
#pragma unroll
        for (int q = 0; q < 4; ++q) { f4 z = {b1q[q], b1q[q], b1q[q], b1q[q]}; acc[0][q] = z; acc[1][q] = z; }
#pragma unroll
        for (int kt = 0; kt < 8; ++kt) {
            const int bufA = (kt < 4) ? cur : old;
            const int ch = (kt < 4) ? (kt * 4 + kg) : (16 + (kt - 4) * 4 + kg);
            h8 a0 = ldx(xs, bufA, lr, ch);
            h8 a1 = ldx(xs, bufA, 16 + lr, ch);
#pragma unroll
            for (int q = 0; q < 4; ++q) {
                acc[0][q] = __builtin_amdgcn_mfma_f32_16x16x32_f16(a0, b1r[kt][q], acc[0][q], 0, 0, 0);
                acc[1][q] = __builtin_amdgcn_mfma_f32_16x16x32_f16(a1, b1r[kt][q], acc[1][q], 0, 0, 0);
            }
        }
        // ===== EW1(i) -> h1(i) into buf cur =====
#pragma unroll
        for (int mt = 0; mt < 2; ++mt)
#pragma unroll
            for (int r = 0; r < 4; ++r) {
                float iv = acc[mt][0][r], fv = acc[mt][1][r], gv = acc[mt][2][r], ov = acc[mt][3][r];
                float c = sigm(fv) * c1[mt][r] + sigm(iv) * tanh_(gv);
                c1[mt][r] = c;
                wrx(xs, cur, mt * 16 + kg * 4 + r, 128 + j, (_Float16)(sigm(ov) * tanh_(c)));
            }
        // ===== G0(i+1): K = [h0(i) buf cur 128 | dyn(i+1) 16 | pad 16] =====
#pragma unroll
        for (int q = 0; q < 4; ++q) { f4 z = {b0q[q], b0q[q], b0q[q], b0q[q]}; acc[0][q] = z; acc[1][q] = z; }
#pragma unroll
        for (int kt = 0; kt < 4; ++kt) {
            h8 a0 = ldx(xs, cur, lr, kt * 4 + kg);
            h8 a1 = ldx(xs, cur, 16 + lr, kt * 4 + kg);
            h8 bq[4];
#pragma unroll
            for (int q = 0; q < 4; ++q)
                bq[q] = *(const h8*)(wb0 + (size_t)(((kt * 4 + kg) * 512 + q * 128 + j) * 8));
#pragma unroll
            for (int q = 0; q < 4; ++q) {
                acc[0][q] = __builtin_amdgcn_mfma_f32_16x16x32_f16(a0, bq[q], acc[0][q], 0, 0, 0);
                acc[1][q] = __builtin_amdgcn_mfma_f32_16x16x32_f16(a1, bq[q], acc[1][q], 0, 0, 0);
            }
        }
#pragma unroll
        for (int q = 0; q < 4; ++q) {
            acc[0][q] = __builtin_amdgcn_mfma_f32_16x16x32_f16(dreg[0], bt[q], acc[0][q], 0, 0, 0);
            acc[1][q] = __builtin_amdgcn_mfma_f32_16x16x32_f16(dreg[1], bt[q], acc[1][q], 0, 0, 0);
        }
        // ===== EW0(i+1) -> h0(i+1) into buf old =====
#pragma unroll
        for (int mt = 0; mt < 2; ++mt)
#pragma unroll
            for (int r = 0; r < 4; ++r) {
                float iv = acc[mt][0][r], fv = acc[mt][1][r], gv = acc[mt][2][r], ov = acc[mt][3][r];
                float c = sigm(fv) * c0[mt][r] + sigm(iv) * tanh_(gv);
                c0[mt][r] = c;
                wrx(xs, old, mt * 16 + kg * 4 + r, j, (_Float16)(sigm(ov) * tanh_(c)));
            }
        // prefetch dyn(i+2)
        if (i < 30 && kg < 2) {
#pragma unroll
            for (int mt = 0; mt < 2; ++mt)
                dreg[mt] = *(const h8*)(dyn16 + (size_t)(row0 + mt * 16 + lr) * 512 + (i + 2) * 16 + (kg & 1) * 8);
        }
    }
    __syncthreads();  // h0(31) visible
    // ===== epilogue: G1(31) + EW1(31) -> rnn =====
    {
        const int cur = 1, old = 0;
        f4 acc[2][4];
#pragma unroll
        for (int q = 0; q < 4; ++q) { f4 z = {b1q[q], b1q[q], b1q[q], b1q[q]}; acc[0][q] = z; acc[1][q] = z; }
#pragma unroll
        for (int kt = 0; kt < 8; ++kt) {
            const int bufA = (kt < 4) ? cur : old;
            const int ch = (kt < 4) ? (kt * 4 + kg) : (16 + (kt - 4) * 4 + kg);
            h8 a0 = ldx(xs, bufA, lr, ch);
            h8 a1 = ldx(xs, bufA, 16 + lr, ch);
#pragma unroll
            for (int q = 0; q < 4; ++q) {
                acc[0][q] = __builtin_amdgcn_mfma_f32_16x16x32_f16(a0, b1r[kt][q], acc[0][q], 0, 0, 0);
                acc[1][q] = __builtin_amdgcn_mfma_f32_16x16x32_f16(a1, b1r[kt][q], acc[1][q], 0, 0, 0);
            }
        }
#pragma unroll
        for (int mt = 0; mt < 2; ++mt)
#pragma unroll
            for (int r = 0; r < 4; ++r) {
                float iv = acc[mt][0][r], fv = acc[mt][1][r], gv = acc[mt][2][r], ov = acc[mt][3][r];
                float c = sigm(fv) * c1[mt][r] + sigm(iv) * tanh_(gv);
                float h = sigm(ov) * tanh_(c);
                rnn[(size_t)(row0 + mt * 16 + kg * 4 + r) * 128 + j] = h;
            }
    }
}

// ---------------- head ----------------
__global__ __launch_bounds__(256) void k_head(const float* __restrict__ gnn, const float* __restrict__ rnn,
                                              const float* __restrict__ fc1w, const float* __restrict__ fc1b,
                                              const float* __restrict__ fbng, const float* __restrict__ fbnb,
                                              const float* __restrict__ fc2w, const float* __restrict__ fc2b,
                                              const float* __restrict__ outw, const float* __restrict__ outb,
                                              float* __restrict__ out) {
    __shared__ __align__(16) float xin[32][196];
    __shared__ __align__(16) float xh2[32][132];
    __shared__ __align__(16) float xh3[32][68];
    const int tid = threadIdx.x;
    const int r0 = blockIdx.x * 32;
    for (int i = tid; i < 32 * 64; i += 256) { int r = i >> 6, c = i & 63; xin[r][c] = gnn[(size_t)(r0 + r) * 64 + c]; }
    for (int i = tid; i < 32 * 128; i += 256) { int r = i >> 7, c = i & 127; xin[r][64 + c] = rnn[(size_t)(r0 + r) * 128 + c]; }
    __syncthreads();
    const int wv = tid >> 6, ln = tid & 63, wr = wv * 8;
    const float rs = rsqrtf(1.0f + 1e-5f);
    float a[8][2];
    float b0 = fc1b[2 * ln], b1 = fc1b[2 * ln + 1];
#pragma unroll
    for (int r = 0; r < 8; ++r) { a[r][0] = b0; a[r][1] = b1; }
    for (int k = 0; k < 192; ++k) {
        v2 w = *(const v2*)&fc1w[k * 128 + 2 * ln];
#pragma unroll
        for (int r = 0; r < 8; ++r) { float x = xin[wr + r][k]; a[r][0] += x * w[0]; a[r][1] += x * w[1]; }
    }
    float s0 = fbng[2 * ln] * rs, s1 = fbng[2 * ln + 1] * rs;
    float bb0 = fbnb[2 * ln], bb1 = fbnb[2 * ln + 1];
#pragma unroll
    for (int r = 0; r < 8; ++r) {
        v2 h;
        h[0] = fmaxf(a[r][0] * s0 + bb0, 0.f);
        h[1] = fmaxf(a[r][1] * s1 + bb1, 0.f);
        *(v2*)&xh2[wr + r][2 * ln] = h;
    }
    __syncthreads();
    float a2[8];
    float b2 = fc2b[ln];
#pragma unroll
    for (int r = 0; r < 8; ++r) a2[r] = b2;
    for (int k = 0; k < 128; ++k) {
        float w = fc2w[k * 64 + ln];
#pragma unroll
        for (int r = 0; r < 8; ++r) a2[r] += xh2[wr + r][k] * w;
    }
#pragma unroll
    for (int r = 0; r < 8; ++r) xh3[wr + r][ln] = fmaxf(a2[r], 0.f);
    __syncthreads();
    if (ln < 10) {
#pragma unroll
        for (int r = 0; r < 8; ++r) {
            float a3 = outb[ln];
            for (int k = 0; k < 64; ++k) a3 += xh3[wr + r][k] * outw[k * 10 + ln];
            out[(size_t)(r0 + wr + r) * 10 + ln] = a3;
        }
    }
}

extern "C" void kernel_launch(void* const* d_in, const int* in_sizes, int n_in,
                              void* d_out, int out_size, void* d_ws, size_t ws_size,
                              hipStream_t stream) {
    const float* dyn  = (const float*)d_in[0];
    const float* xs_  = (const float*)d_in[1];
    const int*   ei   = (const int*)d_in[2];
    const float* g1w  = (const float*)d_in[3];
    const float* g1b  = (const float*)d_in[4];
    const float* g2w  = (const float*)d_in[5];
    const float* g2b  = (const float*)d_in[6];
    const float* bn1g = (const float*)d_in[7];
    const float* bn1b = (const float*)d_in[8];
    const float* bn2g = (const float*)d_in[9];
    const float* bn2b = (const float*)d_in[10];
    const float* wih0 = (const float*)d_in[11];
    const float* whh0 = (const float*)d_in[12];
    const float* bih0 = (const float*)d_in[13];
    const float* bhh0 = (const float*)d_in[14];
    const float* wih1 = (const float*)d_in[15];
    const float* whh1 = (const float*)d_in[16];
    const float* bih1 = (const float*)d_in[17];
    const float* bhh1 = (const float*)d_in[18];
    const float* fc1w = (const float*)d_in[19];
    const float* fc1b = (const float*)d_in[20];
    const float* fbng = (const float*)d_in[21];
    const float* fbnb = (const float*)d_in[22];
    const float* fc2w = (const float*)d_in[23];
    const float* fc2b = (const float*)d_in[24];
    const float* outw = (const float*)d_in[25];
    const float* outb = (const float*)d_in[26];
    float* out = (float*)d_out;

    char* ws = (char*)d_ws;
    _Float16* WB0h  = (_Float16*)(ws + 0);
    _Float16* TLg   = (_Float16*)(ws + 131072);
    _Float16* WB1   = (_Float16*)(ws + 147456);
    _Float16* dyn16 = (_Float16*)(ws + 409600);
    float* fbase = (float*)(ws + 8798208);
    float* bias = fbase;
    float* dis  = fbase + 1024;
    float* hs   = fbase + 9216;
    float* y1   = fbase + 533504;
    float* gnn  = fbase + 1057792;
    float* rnn  = fbase + 1582080;
    int* ibase   = (int*)(ws + 19320832);
    int* cnt     = ibase;
    int* cursor  = ibase + 8192;
    int* rowstart= ibase + 16384;
    int* srcidx  = ibase + 24592;

    const int* srcp = ei;
    const int* dstp = ei + NE;

    k_prep<<<804, 256, 0, stream>>>(wih0, whh0, bih0, bhh0, wih1, whh1, bih1, bhh1, WB0h, TLg, WB1, bias);
    k_cvt_dyn<<<4096, 256, 0, stream>>>(dyn, dyn16);
    hipMemsetAsync(cnt, 0, 2 * 8192 * sizeof(int), stream);
    k_deg_count<<<1024, 256, 0, stream>>>(dstp, cnt);
    k_scan<<<1, 1024, 0, stream>>>(cnt, rowstart, dis);
    k_fill<<<1024, 256, 0, stream>>>(srcp, dstp, rowstart, cursor, srcidx);
    k_gcn_gemm<<<2048, 256, 0, stream>>>(xs_, g1w, dis, hs, 128);
    k_gather<<<2048, 256, 0, stream>>>(hs, srcidx, rowstart, dis, g1b, bn1g, bn1b, y1);
    k_gcn_gemm<<<2048, 256, 0, stream>>>(y1, g2w, dis, hs, 64);
    k_gather<<<2048, 256, 0, stream>>>(hs, srcidx, rowstart, dis, g2b, bn2g, bn2b, gnn);
    k_lstm<<<256, 512, 0, stream>>>(dyn16, WB0h, TLg, WB1, bias, rnn);
    k_head<<<256, 256, 0, stream>>>(gnn, rnn, fc1w, fc1b, fbng, fbnb, fc2w, fc2b, outw, outb, out);
}